// Round 2
// baseline (1383.388 us; speedup 1.0000x reference)
//
#include <hip/hip_runtime.h>
#include <math.h>

#define NN 255
#define MM 300
#define TC 510   // total columns = 2 trees * 255 nodes

__device__ __forceinline__ float sigm(float x) { return 1.0f / (1.0f + expf(-x)); }

// gate a leaf node purely from its xg row (children are zero)
__device__ __forceinline__ void leaf_gate(const float* __restrict__ xgp, int m, float& c, float& h) {
  float x0 = xgp[m], x1 = xgp[300 + m], x3 = xgp[900 + m];
  float u  = tanhf(x0);
  float ig = sigm(x1);
  c = ig * u;
  h = sigm(x3) * tanhf(c);
}

// lightweight grid barrier: device-scope atomics + release/acquire fences.
// Safe cross-XCD: __threadfence() emits wb/inv at agent scope on gfx950.
__device__ __forceinline__ void gsync(unsigned* bar, unsigned nblk) {
  __threadfence();                       // release H/C writes
  __syncthreads();
  if (threadIdx.x == 0) {
    unsigned my = atomicAdd(&bar[1], 0u);
    if (atomicAdd(&bar[0], 1u) == nblk - 1u) {
      atomicExch(&bar[0], 0u);           // reset arrive counter
      __threadfence();                   // order reset before gen bump
      atomicAdd(&bar[1], 1u);            // open the gate
    } else {
      while (atomicAdd(&bar[1], 0u) == my) { __builtin_amdgcn_s_sleep(2); }
    }
  }
  __syncthreads();
  __threadfence();                       // acquire: invalidate stale lines
}

// ---------------- setup: node levels + per-level node lists ----------------
__global__ __launch_bounds__(512) void k_setup(const int* __restrict__ l1, const int* __restrict__ r1,
                                               const int* __restrict__ l2, const int* __restrict__ r2,
                                               int* __restrict__ lists, int* __restrict__ cnt)
{
  __shared__ int lv[TC];
  __shared__ int cs[16];
  int t = threadIdx.x;
  if (t < TC) lv[t] = 0;
  if (t < 16) cs[t] = 0;
  __syncthreads();
  for (int it = 0; it < 12; ++it) {   // parallel relaxation; depth of balanced tree = 7
    int nv = 0;
    if (t < TC) {
      int tr = t >= NN;
      int i  = t - tr * NN;
      const int* L = tr ? l2 : l1;
      const int* R = tr ? r2 : r1;
      int l = L[i], r = R[i];
      nv = (l < 0) ? 0 : 1 + max(lv[tr * NN + l], lv[tr * NN + r]);
    }
    __syncthreads();
    if (t < TC) lv[t] = nv;
    __syncthreads();
  }
  if (t < TC) {
    int tr = t >= NN;
    int i  = t - tr * NN;
    int v  = min(lv[t], 15);
    int pos = atomicAdd(&cs[v], 1);
    lists[v * 256 + pos] = (tr << 8) | i;
  }
  __syncthreads();
  if (t < 16) cnt[t] = cs[t];
}

// ---------------- persistent cooperative tree-LSTM (one launch per stage) ----------------
// 300 blocks x 256 threads. Block = 4 wave-teams; team owns output row m.
// blockIdx = grp*75 + mblk: 4 node-group replicas over 75 m-blocks.
// Weights for all 5 gates of row m live in the team's registers (50 VGPR/lane).
__global__ __launch_bounds__(256, 2) void k_tree(
    const int* __restrict__ l1, const int* __restrict__ r1,
    const int* __restrict__ l2, const int* __restrict__ r2,
    const float* __restrict__ Wl, const float* __restrict__ Wr,
    const float* __restrict__ xg,
    float* __restrict__ H, float* __restrict__ C,
    const int* __restrict__ lists, const int* __restrict__ cnt,
    unsigned* __restrict__ bar)
{
  __shared__ float Hs[4][2][320];
  __shared__ int es[4], lcs[4], rcs[4];

  const int tid  = threadIdx.x;
  const int lane = tid & 63;
  const int team = tid >> 6;
  const int mblk = blockIdx.x % 75;
  const int grp  = blockIdx.x / 75;
  const int m    = mblk * 4 + team;
  const unsigned NB = gridDim.x;

  // ---- one-time: this team's weight slice into registers (K interleaved by lane) ----
  float wl[5][5], wr[5][5];
  #pragma unroll
  for (int g = 0; g < 5; ++g) {
    #pragma unroll
    for (int j = 0; j < 5; ++j) {
      int d = j * 64 + lane;
      size_t o = ((size_t)g * 300 + m) * 300 + d;
      wl[g][j] = (d < 300) ? Wl[o] : 0.f;
      wr[g][j] = (d < 300) ? Wr[o] : 0.f;
    }
  }

  // ---- phase 0: all leaves' H,C ----
  for (int e = blockIdx.x * 256 + tid; e < TC * 300; e += 256 * (int)NB) {
    int gi = e / 300;
    int mm = e - gi * 300;
    int tr = gi >= NN;
    int node = gi - tr * NN;
    const int* L = tr ? l2 : l1;
    if (L[node] < 0) {
      float c, h;
      leaf_gate(xg + (size_t)gi * 1200, mm, c, h);
      C[(size_t)gi * 300 + mm] = c;
      H[(size_t)gi * 300 + mm] = h;
    }
  }
  gsync(bar, NB);

  // ---- levels 1..7 ----
  for (int lv = 1; lv <= 7; ++lv) {
    int nodes = cnt[lv];
    int npg = (nodes + 3) >> 2;
    int n0 = grp * npg;
    int n1 = min(nodes, n0 + npg);
    for (int nb = n0; nb < n1; nb += 4) {
      int nch = min(4, n1 - nb);
      __syncthreads();
      if (tid < nch) {
        int e = lists[lv * 256 + nb + tid];
        int tr = e >> 8, node = e & 255;
        es[tid]  = e;
        lcs[tid] = (tr ? l2 : l1)[node];
        rcs[tid] = (tr ? r2 : r1)[node];
      }
      __syncthreads();
      // stage children H for nch nodes into LDS (pad 300..319 zeroed)
      for (int idx = tid; idx < nch * 640; idx += 256) {
        int ni   = idx / 640;
        int rem  = idx - ni * 640;
        int side = rem >= 320;
        int d    = rem - side * 320;
        float v = 0.f;
        if (d < 300) {
          int tr    = es[ni] >> 8;
          int child = side ? rcs[ni] : lcs[ni];
          v = H[((size_t)(tr * NN + child)) * 300 + d];
        }
        Hs[ni][side][d] = v;
      }
      __syncthreads();
      for (int ni = 0; ni < nch; ++ni) {
        float p0 = 0.f, p1 = 0.f, p2 = 0.f, p3 = 0.f, p4 = 0.f;
        #pragma unroll
        for (int j = 0; j < 5; ++j) {
          float hl = Hs[ni][0][j * 64 + lane];
          float hr = Hs[ni][1][j * 64 + lane];
          p0 += wl[0][j] * hl + wr[0][j] * hr;
          p1 += wl[1][j] * hl + wr[1][j] * hr;
          p2 += wl[2][j] * hl + wr[2][j] * hr;
          p3 += wl[3][j] * hl + wr[3][j] * hr;
          p4 += wl[4][j] * hl + wr[4][j] * hr;
        }
        #pragma unroll
        for (int off = 32; off; off >>= 1) {
          p0 += __shfl_xor(p0, off);
          p1 += __shfl_xor(p1, off);
          p2 += __shfl_xor(p2, off);
          p3 += __shfl_xor(p3, off);
          p4 += __shfl_xor(p4, off);
        }
        if (lane == 0) {
          int e = es[ni];
          int tr = e >> 8, node = e & 255;
          int gi = tr * NN + node;
          float lc = C[(size_t)(tr * NN + lcs[ni]) * 300 + m];
          float rc = C[(size_t)(tr * NN + rcs[ni]) * 300 + m];
          const float* xp = xg + (size_t)gi * 1200;
          float u  = tanhf(xp[m]       + p0);
          float ig = sigm (xp[300 + m] + p1);
          float lf = sigm (xp[600 + m] + p2);
          float rf = sigm (xp[600 + m] + p3);   // fx shared for both forgets
          float o  = sigm (xp[900 + m] + p4);
          float cc = ig * u + lf * lc + rf * rc;
          C[(size_t)gi * 300 + m] = cc;
          H[(size_t)gi * 300 + m] = o * tanhf(cc);
        }
      }
    }
    gsync(bar, NB);
  }
}

// ---------------- xg GEMM: out[col][r] = bias[r] + sum_d W[r][d] * Z[col][d] ----------------
__global__ __launch_bounds__(256) void k_xg(const int* __restrict__ sent1, const int* __restrict__ sent2,
                                            const int* __restrict__ l1, const int* __restrict__ l2,
                                            const float* __restrict__ emb, int pad,
                                            const float* __restrict__ W, const float* __restrict__ bias,
                                            const float* __restrict__ hsrc, float* __restrict__ out)
{
  __shared__ float Z[8][300];
  int tx = threadIdx.x, ty = threadIdx.y;
  int t = ty * 64 + tx;
  int colbase = blockIdx.y * 8;
  for (int c = 0; c < 8; ++c) {
    int gcol = colbase + c;
    if (gcol < TC) {
      if (hsrc) {
        for (int k = t; k < 300; k += 256) Z[c][k] = hsrc[(size_t)gcol * 300 + k];
      } else {
        int tr = gcol >= NN;
        int node = gcol - tr * NN;
        const int* L = tr ? l2 : l1;
        const int* S = tr ? sent2 : sent1;
        int tok = (L[node] < 0) ? S[node] : pad;
        const float* e = emb + (size_t)tok * 300;
        for (int k = t; k < 300; k += 256) Z[c][k] = e[k];
      }
    } else {
      for (int k = t; k < 300; k += 256) Z[c][k] = 0.f;
    }
  }
  __syncthreads();
  int r = blockIdx.x * 64 + tx;
  if (r < 1200) {
    float a0 = 0.f, a1 = 0.f;
    const float* wp = W + (size_t)r * 300;
    for (int k = 0; k < 300; k += 4) {
      float4 wv = *(const float4*)(wp + k);
      float4 z0 = *(const float4*)(&Z[ty][k]);
      float4 z1 = *(const float4*)(&Z[ty + 4][k]);
      a0 += wv.x*z0.x + wv.y*z0.y + wv.z*z0.z + wv.w*z0.w;
      a1 += wv.x*z1.x + wv.y*z1.y + wv.z*z1.z + wv.w*z1.w;
    }
    float b = bias[r];
    int g0 = colbase + ty, g1 = colbase + ty + 4;
    if (g0 < TC) out[(size_t)g0 * 1200 + r] = a0 + b;
    if (g1 < TC) out[(size_t)g1 * 1200 + r] = a1 + b;
  }
}

// ---------------- attention: one block per output row (beta rows then alpha rows) ----------------
__global__ __launch_bounds__(256) void k_attn(const float* __restrict__ Henc, float* __restrict__ ab)
{
  __shared__ float q[300];
  __shared__ float pr[NN];
  __shared__ float red[256];
  int b = blockIdx.x, t = threadIdx.x;
  int dir = b >= NN;
  int i = b - dir * NN;
  const float* Ss = Henc + (dir ? NN * 300 : 0);
  const float* So = Henc + (dir ? 0 : NN * 300);
  for (int k = t; k < 300; k += 256) q[k] = Ss[(size_t)i * 300 + k];
  __syncthreads();
  float v = -1e30f;
  if (t < NN) {
    const float* row = So + (size_t)t * 300;
    float a = 0.f;
    for (int k = 0; k < 300; k += 4) {
      float4 rv = *(const float4*)(row + k);
      float4 qv = *(const float4*)(&q[k]);
      a += rv.x*qv.x + rv.y*qv.y + rv.z*qv.z + rv.w*qv.w;
    }
    pr[t] = a;
    v = a;
  }
  red[t] = v;
  __syncthreads();
  for (int s = 128; s > 0; s >>= 1) { if (t < s) red[t] = fmaxf(red[t], red[t + s]); __syncthreads(); }
  float mx = red[0];
  __syncthreads();
  float e = 0.f;
  if (t < NN) { e = expf(pr[t] - mx); pr[t] = e; }
  red[t] = e;
  __syncthreads();
  for (int s = 128; s > 0; s >>= 1) { if (t < s) red[t] += red[t + s]; __syncthreads(); }
  float inv = 1.0f / red[0];
  __syncthreads();
  for (int m = t; m < 300; m += 256) {
    float a = 0.f;
    for (int j = 0; j < NN; ++j) a += pr[j] * So[(size_t)j * 300 + m];
    ab[(size_t)b * 300 + m] = a * inv;
  }
}

// ---------------- compare h: h = relu(Wc @ [s,a,s-a,s*a] + bc). R=300, K=1200 ----------------
__global__ __launch_bounds__(256) void k_hcmp(const float* __restrict__ Henc, const float* __restrict__ ab,
                                              const float* __restrict__ Wc, const float* __restrict__ bc,
                                              float* __restrict__ hc)
{
  __shared__ float Z[8][1200];
  int tx = threadIdx.x, ty = threadIdx.y;
  int t = ty * 64 + tx;
  int colbase = blockIdx.y * 8;
  for (int c = 0; c < 8; ++c) {
    int gcol = colbase + c;
    if (gcol < TC) {
      const float* sp = Henc + (size_t)gcol * 300;
      const float* ap = ab + (size_t)gcol * 300;
      for (int k = t; k < 1200; k += 256) {
        int sel = k >= 900 ? 3 : (k >= 600 ? 2 : (k >= 300 ? 1 : 0));
        int kk = k - sel * 300;
        float s = sp[kk], a = ap[kk];
        Z[c][k] = sel == 0 ? s : sel == 1 ? a : sel == 2 ? (s - a) : (s * a);
      }
    } else {
      for (int k = t; k < 1200; k += 256) Z[c][k] = 0.f;
    }
  }
  __syncthreads();
  int r = blockIdx.x * 64 + tx;
  if (r < 300) {
    float a0 = 0.f, a1 = 0.f;
    const float* wp = Wc + (size_t)r * 1200;
    for (int k = 0; k < 1200; k += 4) {
      float4 wv = *(const float4*)(wp + k);
      float4 z0 = *(const float4*)(&Z[ty][k]);
      float4 z1 = *(const float4*)(&Z[ty + 4][k]);
      a0 += wv.x*z0.x + wv.y*z0.y + wv.z*z0.z + wv.w*z0.w;
      a1 += wv.x*z1.x + wv.y*z1.y + wv.z*z1.z + wv.w*z1.w;
    }
    float b = bc[r];
    int g0 = colbase + ty, g1 = colbase + ty + 4;
    if (g0 < TC) hc[(size_t)g0 * 300 + r] = fmaxf(a0 + b, 0.f);
    if (g1 < TC) hc[(size_t)g1 * 300 + r] = fmaxf(a1 + b, 0.f);
  }
}

// ---------------- aggregate: mean/max over nodes per tree ----------------
__global__ __launch_bounds__(256) void k_agg(const float* __restrict__ Hcmp, float* __restrict__ agg)
{
  int tr = blockIdx.x, t = threadIdx.x;
  for (int m = t; m < 300; m += 256) {
    float s = 0.f, mx = -1e30f;
    const float* hp = Hcmp + (size_t)tr * NN * 300 + m;
    for (int n = 0; n < NN; ++n) { float v = hp[(size_t)n * 300]; s += v; mx = fmaxf(mx, v); }
    agg[tr * 600 + m] = s / 255.0f;
    agg[tr * 600 + 300 + m] = mx;
  }
}

// ---------------- MLP head ----------------
__global__ __launch_bounds__(512) void k_mlp(const float* __restrict__ agg,
                                             const float* __restrict__ Wa1, const float* __restrict__ ba1,
                                             const float* __restrict__ Wa2, const float* __restrict__ ba2,
                                             float* __restrict__ out)
{
  __shared__ float a_s[1200];
  __shared__ float hid[300];
  int t = threadIdx.x;
  for (int k = t; k < 1200; k += 512) a_s[k] = agg[k];
  __syncthreads();
  for (int h = t; h < 300; h += 512) {
    float acc = ba1[h];
    const float* wp = Wa1 + (size_t)h * 1200;
    for (int k = 0; k < 1200; k += 4) {
      float4 wv = *(const float4*)(wp + k);
      float4 av = *(const float4*)(&a_s[k]);
      acc += wv.x*av.x + wv.y*av.y + wv.z*av.z + wv.w*av.w;
    }
    hid[h] = fmaxf(acc, 0.f);
  }
  __syncthreads();
  if (t < 192) {
    int c = t >> 6, lane = t & 63;
    float a = 0.f;
    for (int k = lane; k < 300; k += 64) a += Wa2[c * 300 + k] * hid[k];
    for (int off = 32; off > 0; off >>= 1) a += __shfl_down(a, off);
    if (lane == 0) out[c] = a + ba2[c];
  }
}

extern "C" void kernel_launch(void* const* d_in, const int* in_sizes, int n_in,
                              void* d_out, int out_size, void* d_ws, size_t ws_size,
                              hipStream_t stream)
{
  const int*   sent1 = (const int*)d_in[0];
  const int*   sent2 = (const int*)d_in[1];
  const int*   l1    = (const int*)d_in[2];
  const int*   r1    = (const int*)d_in[3];
  const int*   l2    = (const int*)d_in[4];
  const int*   r2    = (const int*)d_in[5];
  const float* emb   = (const float*)d_in[6];
  const float* Wx_i  = (const float*)d_in[7];
  const float* bx_i  = (const float*)d_in[8];
  const float* Wl_i  = (const float*)d_in[9];
  const float* Wr_i  = (const float*)d_in[10];
  const float* Wx_c  = (const float*)d_in[11];
  const float* bx_c  = (const float*)d_in[12];
  const float* Wl_c  = (const float*)d_in[13];
  const float* Wr_c  = (const float*)d_in[14];
  const float* Wc    = (const float*)d_in[15];
  const float* bc    = (const float*)d_in[16];
  const float* Wa1   = (const float*)d_in[17];
  const float* ba1   = (const float*)d_in[18];
  const float* Wa2   = (const float*)d_in[19];
  const float* ba2   = (const float*)d_in[20];
  int V = in_sizes[6] / 300;
  int pad = V - 1;

  char* w = (char*)d_ws;
  unsigned* bar = (unsigned*)w;               // 8 B barrier state (reset per call)
  int* cnt   = (int*)(w + 64);                // 16 ints
  int* lists = (int*)(w + 128);               // 16*256 ints
  float* xg   = (float*)(w + 16640);          // [510][1200]
  float* Henc = xg + 612000;                  // [510][300]
  float* Hcmp = Henc + 153000;                // [510][300]
  float* C    = Hcmp + 153000;                // [510][300] (shared across stages)
  float* ab   = C + 153000;                   // [510][300] beta rows then alpha rows
  float* hc   = ab + 153000;                  // [510][300]
  float* agg  = hc + 153000;                  // [1200]

  hipMemsetAsync(bar, 0, 8, stream);
  k_setup<<<1, 512, 0, stream>>>(l1, r1, l2, r2, lists, cnt);

  dim3 blk(64, 4);

  // encode stage
  k_xg<<<dim3(19, 64), blk, 0, stream>>>(sent1, sent2, l1, l2, emb, pad, Wx_i, bx_i, nullptr, xg);
  {
    void* args[] = {(void*)&l1, (void*)&r1, (void*)&l2, (void*)&r2,
                    (void*)&Wl_i, (void*)&Wr_i, (void*)&xg,
                    (void*)&Henc, (void*)&C, (void*)&lists, (void*)&cnt, (void*)&bar};
    hipLaunchCooperativeKernel((void*)k_tree, dim3(300), dim3(256), args, 0, stream);
  }

  // attention
  k_attn<<<TC, 256, 0, stream>>>(Henc, ab);

  // compare stage
  k_hcmp<<<dim3(5, 64), blk, 0, stream>>>(Henc, ab, Wc, bc, hc);
  k_xg<<<dim3(19, 64), blk, 0, stream>>>(sent1, sent2, l1, l2, emb, pad, Wx_c, bx_c, hc, xg);
  {
    void* args[] = {(void*)&l1, (void*)&r1, (void*)&l2, (void*)&r2,
                    (void*)&Wl_c, (void*)&Wr_c, (void*)&xg,
                    (void*)&Hcmp, (void*)&C, (void*)&lists, (void*)&cnt, (void*)&bar};
    hipLaunchCooperativeKernel((void*)k_tree, dim3(300), dim3(256), args, 0, stream);
  }

  // head
  k_agg<<<2, 256, 0, stream>>>(Hcmp, agg);
  k_mlp<<<1, 512, 0, stream>>>(agg, Wa1, ba1, Wa2, ba2, (float*)d_out);
}

// Round 3
// 625.955 us; speedup vs baseline: 2.2100x; 2.2100x over previous
//
#include <hip/hip_runtime.h>
#include <math.h>

#define NN 255
#define MM 300
#define TC 510    // total columns = 2 trees * 255 nodes
#define NBLK 300  // cooperative grid size
#define CHUNK 8   // nodes per LDS chunk in k_tree

__device__ __forceinline__ float sigm(float x) { return 1.0f / (1.0f + expf(-x)); }

// relaxed agent-scope accessors: coherent at the device point, no cache flushes
__device__ __forceinline__ float aload(const float* p) {
  return __hip_atomic_load(p, __ATOMIC_RELAXED, __HIP_MEMORY_SCOPE_AGENT);
}
__device__ __forceinline__ void astore(float* p, float v) {
  __hip_atomic_store(p, v, __ATOMIC_RELAXED, __HIP_MEMORY_SCOPE_AGENT);
}

// gate a leaf node purely from its xg row (children are zero)
__device__ __forceinline__ void leaf_gate(const float* __restrict__ xgp, int m, float& c, float& h) {
  float x0 = xgp[m], x1 = xgp[300 + m], x3 = xgp[900 + m];
  float u  = tanhf(x0);
  float ig = sigm(x1);
  c = ig * u;
  h = sigm(x3) * tanhf(c);
}

// grid barrier: monotonic phase, relaxed agent atomics only (NO cache maintenance).
// Each wave drains its own vmcnt (sc1 stores are then agent-visible), block syncs,
// one thread arrives; gate is a monotonic phase number.
__device__ __forceinline__ void gsync(unsigned* bar, unsigned phase) {
  asm volatile("s_waitcnt vmcnt(0)" ::: "memory");
  __syncthreads();
  if (threadIdx.x == 0) {
    unsigned old = __hip_atomic_fetch_add(&bar[0], 1u, __ATOMIC_RELAXED, __HIP_MEMORY_SCOPE_AGENT);
    if (old == phase * (unsigned)NBLK - 1u) {
      __hip_atomic_store(&bar[1], phase, __ATOMIC_RELAXED, __HIP_MEMORY_SCOPE_AGENT);
    } else {
      while (__hip_atomic_load(&bar[1], __ATOMIC_RELAXED, __HIP_MEMORY_SCOPE_AGENT) < phase)
        __builtin_amdgcn_s_sleep(4);
    }
  }
  __syncthreads();
}

// ---------------- setup: node levels + per-level node lists ----------------
__global__ __launch_bounds__(512) void k_setup(const int* __restrict__ l1, const int* __restrict__ r1,
                                               const int* __restrict__ l2, const int* __restrict__ r2,
                                               int* __restrict__ lists, int* __restrict__ cnt)
{
  __shared__ int lv[TC];
  __shared__ int cs[16];
  int t = threadIdx.x;
  if (t < TC) lv[t] = 0;
  if (t < 16) cs[t] = 0;
  __syncthreads();
  for (int it = 0; it < 12; ++it) {
    int nv = 0;
    if (t < TC) {
      int tr = t >= NN;
      int i  = t - tr * NN;
      const int* L = tr ? l2 : l1;
      const int* R = tr ? r2 : r1;
      int l = L[i], r = R[i];
      nv = (l < 0) ? 0 : 1 + max(lv[tr * NN + l], lv[tr * NN + r]);
    }
    __syncthreads();
    if (t < TC) lv[t] = nv;
    __syncthreads();
  }
  if (t < TC) {
    int tr = t >= NN;
    int i  = t - tr * NN;
    int v  = min(lv[t], 15);
    int pos = atomicAdd(&cs[v], 1);
    lists[v * 256 + pos] = (tr << 8) | i;
  }
  __syncthreads();
  if (t < 16) cnt[t] = cs[t];
}

// ---------------- persistent cooperative tree-LSTM (one launch per stage) ----------------
// 300 blocks x 256 threads. Block = 4 wave-teams; team owns output row m.
// blockIdx = grp*75 + mblk: 4 node-group partitions x 75 m-blocks.
// Weights for all 5 gates of row m live in the team's registers (50 VGPR/lane);
// they stream from L2 which now stays warm (no fences anywhere in the kernel).
__global__ __launch_bounds__(256, 2) void k_tree(
    const int* __restrict__ l1, const int* __restrict__ r1,
    const int* __restrict__ l2, const int* __restrict__ r2,
    const float* __restrict__ Wl, const float* __restrict__ Wr,
    const float* __restrict__ xg,
    float* __restrict__ H, float* __restrict__ C,
    const int* __restrict__ lists, const int* __restrict__ cnt,
    unsigned* __restrict__ bar)
{
  __shared__ float Hs[CHUNK][2][320];
  __shared__ float Cs[CHUNK][4][2];
  __shared__ float Xs[CHUNK][4][4];
  __shared__ int es[CHUNK], lcs[CHUNK], rcs[CHUNK];

  const int tid  = threadIdx.x;
  const int lane = tid & 63;
  const int team = tid >> 6;
  const int mblk = blockIdx.x % 75;
  const int grp  = blockIdx.x / 75;
  const int m    = mblk * 4 + team;

  // ---- one-time: this team's weight slice into registers (K interleaved by lane) ----
  float wl[5][5], wr[5][5];
  #pragma unroll
  for (int g = 0; g < 5; ++g) {
    #pragma unroll
    for (int j = 0; j < 5; ++j) {
      int d = j * 64 + lane;
      size_t o = ((size_t)g * 300 + m) * 300 + d;
      wl[g][j] = (d < 300) ? Wl[o] : 0.f;
      wr[g][j] = (d < 300) ? Wr[o] : 0.f;
    }
  }

  // ---- phase 0: all leaves' H,C (agent stores: cross-block readable) ----
  for (int e = blockIdx.x * 256 + tid; e < TC * 300; e += 256 * NBLK) {
    int gi = e / 300;
    int mm = e - gi * 300;
    int tr = gi >= NN;
    int node = gi - tr * NN;
    if ((tr ? l2 : l1)[node] < 0) {
      float c, h;
      leaf_gate(xg + (size_t)gi * 1200, mm, c, h);
      astore(&C[(size_t)gi * 300 + mm], c);
      astore(&H[(size_t)gi * 300 + mm], h);
    }
  }
  gsync(bar, 1);

  // ---- levels 1..7 ----
  for (int lv = 1; lv <= 7; ++lv) {
    int nodes = cnt[lv];
    int npg = (nodes + 3) >> 2;
    int n0 = grp * npg;
    int n1 = min(nodes, n0 + npg);
    for (int nb = n0; nb < n1; nb += CHUNK) {
      int nch = min(CHUNK, n1 - nb);
      __syncthreads();   // previous chunk's tails done with LDS
      if (tid < nch) {
        int e = lists[lv * 256 + nb + tid];
        int tr = e >> 8, node = e & 255;
        es[tid]  = e;
        lcs[tid] = (tr ? l2 : l1)[node];
        rcs[tid] = (tr ? r2 : r1)[node];
      }
      __syncthreads();
      // prefetch children C (agent) and xg gate terms (cached) for the gating tails
      if (tid < nch * 8) {
        int ni = tid >> 3, tm = (tid >> 1) & 3, side = tid & 1;
        int tr = es[ni] >> 8;
        int child = side ? rcs[ni] : lcs[ni];
        Cs[ni][tm][side] = aload(&C[(size_t)(tr * NN + child) * 300 + mblk * 4 + tm]);
      }
      {
        int q = tid - 128;
        if (q >= 0 && q < nch * 16) {
          int ni = q >> 4, tm = (q >> 2) & 3, g = q & 3;
          int e = es[ni];
          int gi = (e >> 8) * NN + (e & 255);
          Xs[ni][tm][g] = xg[(size_t)gi * 1200 + g * 300 + mblk * 4 + tm];
        }
      }
      // stage children H for nch nodes into LDS (pad 300..319 zeroed)
      for (int idx = tid; idx < nch * 640; idx += 256) {
        int ni   = idx / 640;
        int rem  = idx - ni * 640;
        int side = rem >= 320;
        int d    = rem - side * 320;
        float v = 0.f;
        if (d < 300) {
          int tr    = es[ni] >> 8;
          int child = side ? rcs[ni] : lcs[ni];
          v = aload(&H[(size_t)(tr * NN + child) * 300 + d]);
        }
        Hs[ni][side][d] = v;
      }
      __syncthreads();
      #pragma unroll 2
      for (int ni = 0; ni < nch; ++ni) {
        float p0 = 0.f, p1 = 0.f, p2 = 0.f, p3 = 0.f, p4 = 0.f;
        #pragma unroll
        for (int j = 0; j < 5; ++j) {
          float hl = Hs[ni][0][j * 64 + lane];
          float hr = Hs[ni][1][j * 64 + lane];
          p0 += wl[0][j] * hl + wr[0][j] * hr;
          p1 += wl[1][j] * hl + wr[1][j] * hr;
          p2 += wl[2][j] * hl + wr[2][j] * hr;
          p3 += wl[3][j] * hl + wr[3][j] * hr;
          p4 += wl[4][j] * hl + wr[4][j] * hr;
        }
        #pragma unroll
        for (int off = 32; off; off >>= 1) {
          p0 += __shfl_xor(p0, off);
          p1 += __shfl_xor(p1, off);
          p2 += __shfl_xor(p2, off);
          p3 += __shfl_xor(p3, off);
          p4 += __shfl_xor(p4, off);
        }
        if (lane == 0) {
          int e = es[ni];
          int gi = (e >> 8) * NN + (e & 255);
          float lc = Cs[ni][team][0], rc = Cs[ni][team][1];
          float u  = tanhf(Xs[ni][team][0] + p0);
          float ig = sigm (Xs[ni][team][1] + p1);
          float lf = sigm (Xs[ni][team][2] + p2);
          float rf = sigm (Xs[ni][team][2] + p3);   // fx shared for both forgets
          float o  = sigm (Xs[ni][team][3] + p4);
          float cc = ig * u + lf * lc + rf * rc;
          astore(&C[(size_t)gi * 300 + m], cc);
          astore(&H[(size_t)gi * 300 + m], o * tanhf(cc));
        }
      }
    }
    if (lv < 7) gsync(bar, 1 + lv);
  }
}

// ---------------- xg GEMM: out[col][r] = bias[r] + sum_d W[r][d] * Z[col][d] ----------------
__global__ __launch_bounds__(256) void k_xg(const int* __restrict__ sent1, const int* __restrict__ sent2,
                                            const int* __restrict__ l1, const int* __restrict__ l2,
                                            const float* __restrict__ emb, int pad,
                                            const float* __restrict__ W, const float* __restrict__ bias,
                                            const float* __restrict__ hsrc, float* __restrict__ out)
{
  __shared__ float Z[8][300];
  int tx = threadIdx.x, ty = threadIdx.y;
  int t = ty * 64 + tx;
  int colbase = blockIdx.y * 8;
  for (int c = 0; c < 8; ++c) {
    int gcol = colbase + c;
    if (gcol < TC) {
      if (hsrc) {
        for (int k = t; k < 300; k += 256) Z[c][k] = hsrc[(size_t)gcol * 300 + k];
      } else {
        int tr = gcol >= NN;
        int node = gcol - tr * NN;
        const int* L = tr ? l2 : l1;
        const int* S = tr ? sent2 : sent1;
        int tok = (L[node] < 0) ? S[node] : pad;
        const float* e = emb + (size_t)tok * 300;
        for (int k = t; k < 300; k += 256) Z[c][k] = e[k];
      }
    } else {
      for (int k = t; k < 300; k += 256) Z[c][k] = 0.f;
    }
  }
  __syncthreads();
  int r = blockIdx.x * 64 + tx;
  if (r < 1200) {
    float a0 = 0.f, a1 = 0.f;
    const float* wp = W + (size_t)r * 300;
    for (int k = 0; k < 300; k += 4) {
      float4 wv = *(const float4*)(wp + k);
      float4 z0 = *(const float4*)(&Z[ty][k]);
      float4 z1 = *(const float4*)(&Z[ty + 4][k]);
      a0 += wv.x*z0.x + wv.y*z0.y + wv.z*z0.z + wv.w*z0.w;
      a1 += wv.x*z1.x + wv.y*z1.y + wv.z*z1.z + wv.w*z1.w;
    }
    float b = bias[r];
    int g0 = colbase + ty, g1 = colbase + ty + 4;
    if (g0 < TC) out[(size_t)g0 * 1200 + r] = a0 + b;
    if (g1 < TC) out[(size_t)g1 * 1200 + r] = a1 + b;
  }
}

// ---------------- attention: one block per output row (beta rows then alpha rows) ----------------
__global__ __launch_bounds__(256) void k_attn(const float* __restrict__ Henc, float* __restrict__ ab)
{
  __shared__ float q[300];
  __shared__ float pr[NN];
  __shared__ float red[256];
  int b = blockIdx.x, t = threadIdx.x;
  int dir = b >= NN;
  int i = b - dir * NN;
  const float* Ss = Henc + (dir ? NN * 300 : 0);
  const float* So = Henc + (dir ? 0 : NN * 300);
  for (int k = t; k < 300; k += 256) q[k] = Ss[(size_t)i * 300 + k];
  __syncthreads();
  float v = -1e30f;
  if (t < NN) {
    const float* row = So + (size_t)t * 300;
    float a = 0.f;
    for (int k = 0; k < 300; k += 4) {
      float4 rv = *(const float4*)(row + k);
      float4 qv = *(const float4*)(&q[k]);
      a += rv.x*qv.x + rv.y*qv.y + rv.z*qv.z + rv.w*qv.w;
    }
    pr[t] = a;
    v = a;
  }
  red[t] = v;
  __syncthreads();
  for (int s = 128; s > 0; s >>= 1) { if (t < s) red[t] = fmaxf(red[t], red[t + s]); __syncthreads(); }
  float mx = red[0];
  __syncthreads();
  float e = 0.f;
  if (t < NN) { e = expf(pr[t] - mx); pr[t] = e; }
  red[t] = e;
  __syncthreads();
  for (int s = 128; s > 0; s >>= 1) { if (t < s) red[t] += red[t + s]; __syncthreads(); }
  float inv = 1.0f / red[0];
  __syncthreads();
  for (int m = t; m < 300; m += 256) {
    float a = 0.f;
    for (int j = 0; j < NN; ++j) a += pr[j] * So[(size_t)j * 300 + m];
    ab[(size_t)b * 300 + m] = a * inv;
  }
}

// ---------------- compare h: h = relu(Wc @ [s,a,s-a,s*a] + bc). R=300, K=1200 ----------------
__global__ __launch_bounds__(256) void k_hcmp(const float* __restrict__ Henc, const float* __restrict__ ab,
                                              const float* __restrict__ Wc, const float* __restrict__ bc,
                                              float* __restrict__ hc)
{
  __shared__ float Z[8][1200];
  int tx = threadIdx.x, ty = threadIdx.y;
  int t = ty * 64 + tx;
  int colbase = blockIdx.y * 8;
  for (int c = 0; c < 8; ++c) {
    int gcol = colbase + c;
    if (gcol < TC) {
      const float* sp = Henc + (size_t)gcol * 300;
      const float* ap = ab + (size_t)gcol * 300;
      for (int k = t; k < 1200; k += 256) {
        int sel = k >= 900 ? 3 : (k >= 600 ? 2 : (k >= 300 ? 1 : 0));
        int kk = k - sel * 300;
        float s = sp[kk], a = ap[kk];
        Z[c][k] = sel == 0 ? s : sel == 1 ? a : sel == 2 ? (s - a) : (s * a);
      }
    } else {
      for (int k = t; k < 1200; k += 256) Z[c][k] = 0.f;
    }
  }
  __syncthreads();
  int r = blockIdx.x * 64 + tx;
  if (r < 300) {
    float a0 = 0.f, a1 = 0.f;
    const float* wp = Wc + (size_t)r * 1200;
    for (int k = 0; k < 1200; k += 4) {
      float4 wv = *(const float4*)(wp + k);
      float4 z0 = *(const float4*)(&Z[ty][k]);
      float4 z1 = *(const float4*)(&Z[ty + 4][k]);
      a0 += wv.x*z0.x + wv.y*z0.y + wv.z*z0.z + wv.w*z0.w;
      a1 += wv.x*z1.x + wv.y*z1.y + wv.z*z1.z + wv.w*z1.w;
    }
    float b = bc[r];
    int g0 = colbase + ty, g1 = colbase + ty + 4;
    if (g0 < TC) hc[(size_t)g0 * 300 + r] = fmaxf(a0 + b, 0.f);
    if (g1 < TC) hc[(size_t)g1 * 300 + r] = fmaxf(a1 + b, 0.f);
  }
}

// ---------------- aggregate: mean/max over nodes per tree ----------------
__global__ __launch_bounds__(256) void k_agg(const float* __restrict__ Hcmp, float* __restrict__ agg)
{
  int tr = blockIdx.x, t = threadIdx.x;
  for (int m = t; m < 300; m += 256) {
    float s = 0.f, mx = -1e30f;
    const float* hp = Hcmp + (size_t)tr * NN * 300 + m;
    for (int n = 0; n < NN; ++n) { float v = hp[(size_t)n * 300]; s += v; mx = fmaxf(mx, v); }
    agg[tr * 600 + m] = s / 255.0f;
    agg[tr * 600 + 300 + m] = mx;
  }
}

// ---------------- MLP head ----------------
__global__ __launch_bounds__(512) void k_mlp(const float* __restrict__ agg,
                                             const float* __restrict__ Wa1, const float* __restrict__ ba1,
                                             const float* __restrict__ Wa2, const float* __restrict__ ba2,
                                             float* __restrict__ out)
{
  __shared__ float a_s[1200];
  __shared__ float hid[300];
  int t = threadIdx.x;
  for (int k = t; k < 1200; k += 512) a_s[k] = agg[k];
  __syncthreads();
  for (int h = t; h < 300; h += 512) {
    float acc = ba1[h];
    const float* wp = Wa1 + (size_t)h * 1200;
    for (int k = 0; k < 1200; k += 4) {
      float4 wv = *(const float4*)(wp + k);
      float4 av = *(const float4*)(&a_s[k]);
      acc += wv.x*av.x + wv.y*av.y + wv.z*av.z + wv.w*av.w;
    }
    hid[h] = fmaxf(acc, 0.f);
  }
  __syncthreads();
  if (t < 192) {
    int c = t >> 6, lane = t & 63;
    float a = 0.f;
    for (int k = lane; k < 300; k += 64) a += Wa2[c * 300 + k] * hid[k];
    for (int off = 32; off > 0; off >>= 1) a += __shfl_down(a, off);
    if (lane == 0) out[c] = a + ba2[c];
  }
}

extern "C" void kernel_launch(void* const* d_in, const int* in_sizes, int n_in,
                              void* d_out, int out_size, void* d_ws, size_t ws_size,
                              hipStream_t stream)
{
  const int*   sent1 = (const int*)d_in[0];
  const int*   sent2 = (const int*)d_in[1];
  const int*   l1    = (const int*)d_in[2];
  const int*   r1    = (const int*)d_in[3];
  const int*   l2    = (const int*)d_in[4];
  const int*   r2    = (const int*)d_in[5];
  const float* emb   = (const float*)d_in[6];
  const float* Wx_i  = (const float*)d_in[7];
  const float* bx_i  = (const float*)d_in[8];
  const float* Wl_i  = (const float*)d_in[9];
  const float* Wr_i  = (const float*)d_in[10];
  const float* Wx_c  = (const float*)d_in[11];
  const float* bx_c  = (const float*)d_in[12];
  const float* Wl_c  = (const float*)d_in[13];
  const float* Wr_c  = (const float*)d_in[14];
  const float* Wc    = (const float*)d_in[15];
  const float* bc    = (const float*)d_in[16];
  const float* Wa1   = (const float*)d_in[17];
  const float* ba1   = (const float*)d_in[18];
  const float* Wa2   = (const float*)d_in[19];
  const float* ba2   = (const float*)d_in[20];
  int V = in_sizes[6] / 300;
  int pad = V - 1;

  char* w = (char*)d_ws;
  unsigned* bar1 = (unsigned*)w;              // barrier state, stage 1
  unsigned* bar2 = (unsigned*)(w + 64);       // barrier state, stage 2
  int* cnt   = (int*)(w + 128);               // 16 ints
  int* lists = (int*)(w + 192);               // 16*256 ints
  float* xg   = (float*)(w + 16640);          // [510][1200]
  float* Henc = xg + 612000;                  // [510][300]
  float* Hcmp = Henc + 153000;                // [510][300]
  float* C    = Hcmp + 153000;                // [510][300] (shared across stages)
  float* ab   = C + 153000;                   // [510][300] beta rows then alpha rows
  float* hc   = ab + 153000;                  // [510][300]
  float* agg  = hc + 153000;                  // [1200]

  hipMemsetAsync((void*)bar1, 0, 128, stream);
  k_setup<<<1, 512, 0, stream>>>(l1, r1, l2, r2, lists, cnt);

  dim3 blk(64, 4);

  // encode stage
  k_xg<<<dim3(19, 64), blk, 0, stream>>>(sent1, sent2, l1, l2, emb, pad, Wx_i, bx_i, nullptr, xg);
  {
    void* args[] = {(void*)&l1, (void*)&r1, (void*)&l2, (void*)&r2,
                    (void*)&Wl_i, (void*)&Wr_i, (void*)&xg,
                    (void*)&Henc, (void*)&C, (void*)&lists, (void*)&cnt, (void*)&bar1};
    hipLaunchCooperativeKernel((void*)k_tree, dim3(NBLK), dim3(256), args, 0, stream);
  }

  // attention
  k_attn<<<TC, 256, 0, stream>>>(Henc, ab);

  // compare stage
  k_hcmp<<<dim3(5, 64), blk, 0, stream>>>(Henc, ab, Wc, bc, hc);
  k_xg<<<dim3(19, 64), blk, 0, stream>>>(sent1, sent2, l1, l2, emb, pad, Wx_c, bx_c, hc, xg);
  {
    void* args[] = {(void*)&l1, (void*)&r1, (void*)&l2, (void*)&r2,
                    (void*)&Wl_c, (void*)&Wr_c, (void*)&xg,
                    (void*)&Hcmp, (void*)&C, (void*)&lists, (void*)&cnt, (void*)&bar2};
    hipLaunchCooperativeKernel((void*)k_tree, dim3(NBLK), dim3(256), args, 0, stream);
  }

  // head
  k_agg<<<2, 256, 0, stream>>>(Hcmp, agg);
  k_mlp<<<1, 512, 0, stream>>>(agg, Wa1, ba1, Wa2, ba2, (float*)d_out);
}

// Round 4
// 550.700 us; speedup vs baseline: 2.5121x; 1.1367x over previous
//
#include <hip/hip_runtime.h>
#include <math.h>

#define NN 255
#define MM 300
#define TC 510    // total columns = 2 trees * 255 nodes
#define NBLK 300  // cooperative grid size
#define CHUNK 16  // nodes per LDS chunk in k_tree

__device__ __forceinline__ float sigm(float x) { return 1.0f / (1.0f + expf(-x)); }

// relaxed agent-scope accessors: coherent at the device point, no cache flushes
__device__ __forceinline__ float aload(const float* p) {
  return __hip_atomic_load(p, __ATOMIC_RELAXED, __HIP_MEMORY_SCOPE_AGENT);
}
__device__ __forceinline__ void astore(float* p, float v) {
  __hip_atomic_store(p, v, __ATOMIC_RELAXED, __HIP_MEMORY_SCOPE_AGENT);
}

// gate a leaf node purely from its xg row (children are zero)
__device__ __forceinline__ void leaf_gate(const float* __restrict__ xgp, int m, float& c, float& h) {
  float x0 = xgp[m], x1 = xgp[300 + m], x3 = xgp[900 + m];
  float u  = tanhf(x0);
  float ig = sigm(x1);
  c = ig * u;
  h = sigm(x3) * tanhf(c);
}

// Contention-free grid barrier: per-block flag (plain relaxed store, no RMW),
// block 0 wave 0 scans flags (5 vector loads/lane) and opens a monotonic gate.
// vmcnt drain before arrival makes all prior sc1 stores agent-visible.
__device__ __forceinline__ void gsync(unsigned* flags, unsigned phase) {
  asm volatile("s_waitcnt vmcnt(0)" ::: "memory");
  __syncthreads();
  unsigned* gate = flags + NBLK;
  if (blockIdx.x == 0) {
    if (threadIdx.x < 64) {
      for (;;) {
        unsigned mn = phase;
        for (int i = 1 + (int)threadIdx.x; i < NBLK; i += 64)
          mn = min(mn, __hip_atomic_load(&flags[i], __ATOMIC_RELAXED, __HIP_MEMORY_SCOPE_AGENT));
        if (__all(mn >= phase)) break;
        __builtin_amdgcn_s_sleep(2);
      }
      if (threadIdx.x == 0)
        __hip_atomic_store(gate, phase, __ATOMIC_RELAXED, __HIP_MEMORY_SCOPE_AGENT);
    }
  } else {
    if (threadIdx.x == 0) {
      __hip_atomic_store(&flags[blockIdx.x], phase, __ATOMIC_RELAXED, __HIP_MEMORY_SCOPE_AGENT);
      while (__hip_atomic_load(gate, __ATOMIC_RELAXED, __HIP_MEMORY_SCOPE_AGENT) < phase)
        __builtin_amdgcn_s_sleep(2);
    }
  }
  __syncthreads();
}

// ---------------- setup: node levels + per-level node lists ----------------
__global__ __launch_bounds__(512) void k_setup(const int* __restrict__ l1, const int* __restrict__ r1,
                                               const int* __restrict__ l2, const int* __restrict__ r2,
                                               int* __restrict__ lists, int* __restrict__ cnt)
{
  __shared__ int lv[TC];
  __shared__ int cs[16];
  int t = threadIdx.x;
  if (t < TC) lv[t] = 0;
  if (t < 16) cs[t] = 0;
  __syncthreads();
  for (int it = 0; it < 12; ++it) {
    int nv = 0;
    if (t < TC) {
      int tr = t >= NN;
      int i  = t - tr * NN;
      const int* L = tr ? l2 : l1;
      const int* R = tr ? r2 : r1;
      int l = L[i], r = R[i];
      nv = (l < 0) ? 0 : 1 + max(lv[tr * NN + l], lv[tr * NN + r]);
    }
    __syncthreads();
    if (t < TC) lv[t] = nv;
    __syncthreads();
  }
  if (t < TC) {
    int tr = t >= NN;
    int i  = t - tr * NN;
    int v  = min(lv[t], 15);
    int pos = atomicAdd(&cs[v], 1);
    lists[v * 256 + pos] = (tr << 8) | i;
  }
  __syncthreads();
  if (t < 16) cnt[t] = cs[t];
}

// ---------------- persistent cooperative tree-LSTM (one launch per stage) ----------------
// 300 blocks x 256 threads. Block = 4 wave-teams; team owns output row m.
// blockIdx = grp*75 + mblk: 4 node-group partitions x 75 m-blocks.
// Weights for all 5 gates of row m live in the team's registers (50 VGPR/lane).
__global__ __launch_bounds__(256, 2) void k_tree(
    const int* __restrict__ l1, const int* __restrict__ r1,
    const int* __restrict__ l2, const int* __restrict__ r2,
    const float* __restrict__ Wl, const float* __restrict__ Wr,
    const float* __restrict__ xg,
    float* __restrict__ H, float* __restrict__ C,
    const int* __restrict__ lists, const int* __restrict__ cnt,
    unsigned* __restrict__ bar)
{
  __shared__ float Hs[CHUNK][2][320];
  __shared__ float Cs[CHUNK][4][2];
  __shared__ float Xs[CHUNK][4][4];
  __shared__ int es[CHUNK], lcs[CHUNK], rcs[CHUNK];

  const int tid  = threadIdx.x;
  const int lane = tid & 63;
  const int team = tid >> 6;
  const int mblk = blockIdx.x % 75;
  const int grp  = blockIdx.x / 75;
  const int m    = mblk * 4 + team;

  // ---- one-time: this team's weight slice into registers (K interleaved by lane) ----
  float wl[5][5], wr[5][5];
  #pragma unroll
  for (int g = 0; g < 5; ++g) {
    #pragma unroll
    for (int j = 0; j < 5; ++j) {
      int d = j * 64 + lane;
      size_t o = ((size_t)g * 300 + m) * 300 + d;
      wl[g][j] = (d < 300) ? Wl[o] : 0.f;
      wr[g][j] = (d < 300) ? Wr[o] : 0.f;
    }
  }

  // ---- phase 0: all leaves' H,C (agent stores: cross-block readable) ----
  for (int e = blockIdx.x * 256 + tid; e < TC * 300; e += 256 * NBLK) {
    int gi = e / 300;
    int mm = e - gi * 300;
    int tr = gi >= NN;
    int node = gi - tr * NN;
    if ((tr ? l2 : l1)[node] < 0) {
      float c, h;
      leaf_gate(xg + (size_t)gi * 1200, mm, c, h);
      astore(&C[(size_t)gi * 300 + mm], c);
      astore(&H[(size_t)gi * 300 + mm], h);
    }
  }
  gsync(bar, 1);

  // ---- levels 1..7 ----
  for (int lv = 1; lv <= 7; ++lv) {
    int nodes = cnt[lv];
    int npg = (nodes + 3) >> 2;
    int n0 = grp * npg;
    int n1 = min(nodes, n0 + npg);
    for (int nb = n0; nb < n1; nb += CHUNK) {
      int nch = min(CHUNK, n1 - nb);
      __syncthreads();   // previous chunk's tails done with LDS
      if (tid < nch) {
        int e = lists[lv * 256 + nb + tid];
        int tr = e >> 8, node = e & 255;
        es[tid]  = e;
        lcs[tid] = (tr ? l2 : l1)[node];
        rcs[tid] = (tr ? r2 : r1)[node];
      }
      __syncthreads();
      // prefetch children C (agent) and xg gate terms (cached) for the gating tails
      for (int q = tid; q < nch * 8; q += 256) {
        int ni = q >> 3, tm = (q >> 1) & 3, side = q & 1;
        int tr = es[ni] >> 8;
        int child = side ? rcs[ni] : lcs[ni];
        Cs[ni][tm][side] = aload(&C[(size_t)(tr * NN + child) * 300 + mblk * 4 + tm]);
      }
      for (int q = tid; q < nch * 16; q += 256) {
        int ni = q >> 4, tm = (q >> 2) & 3, g = q & 3;
        int e = es[ni];
        int gi = (e >> 8) * NN + (e & 255);
        Xs[ni][tm][g] = xg[(size_t)gi * 1200 + g * 300 + mblk * 4 + tm];
      }
      // stage children H for nch nodes into LDS (pad 300..319 zeroed)
      for (int idx = tid; idx < nch * 640; idx += 256) {
        int ni   = idx / 640;
        int rem  = idx - ni * 640;
        int side = rem >= 320;
        int d    = rem - side * 320;
        float v = 0.f;
        if (d < 300) {
          int tr    = es[ni] >> 8;
          int child = side ? rcs[ni] : lcs[ni];
          v = aload(&H[(size_t)(tr * NN + child) * 300 + d]);
        }
        Hs[ni][side][d] = v;
      }
      __syncthreads();
      #pragma unroll 2
      for (int ni = 0; ni < nch; ++ni) {
        float p0 = 0.f, p1 = 0.f, p2 = 0.f, p3 = 0.f, p4 = 0.f;
        #pragma unroll
        for (int j = 0; j < 5; ++j) {
          float hl = Hs[ni][0][j * 64 + lane];
          float hr = Hs[ni][1][j * 64 + lane];
          p0 += wl[0][j] * hl + wr[0][j] * hr;
          p1 += wl[1][j] * hl + wr[1][j] * hr;
          p2 += wl[2][j] * hl + wr[2][j] * hr;
          p3 += wl[3][j] * hl + wr[3][j] * hr;
          p4 += wl[4][j] * hl + wr[4][j] * hr;
        }
        #pragma unroll
        for (int off = 32; off; off >>= 1) {
          p0 += __shfl_xor(p0, off);
          p1 += __shfl_xor(p1, off);
          p2 += __shfl_xor(p2, off);
          p3 += __shfl_xor(p3, off);
          p4 += __shfl_xor(p4, off);
        }
        if (lane == 0) {
          int e = es[ni];
          int gi = (e >> 8) * NN + (e & 255);
          float lc = Cs[ni][team][0], rc = Cs[ni][team][1];
          float u  = tanhf(Xs[ni][team][0] + p0);
          float ig = sigm (Xs[ni][team][1] + p1);
          float lf = sigm (Xs[ni][team][2] + p2);
          float rf = sigm (Xs[ni][team][2] + p3);   // fx shared for both forgets
          float o  = sigm (Xs[ni][team][3] + p4);
          float cc = ig * u + lf * lc + rf * rc;
          astore(&C[(size_t)gi * 300 + m], cc);
          astore(&H[(size_t)gi * 300 + m], o * tanhf(cc));
        }
      }
    }
    if (lv < 7) gsync(bar, 1 + lv);
  }
}

// ---------------- xg GEMM: out[col][r] = bias[r] + sum_d W[r][d] * Z[col][d] ----------------
__global__ __launch_bounds__(256) void k_xg(const int* __restrict__ sent1, const int* __restrict__ sent2,
                                            const int* __restrict__ l1, const int* __restrict__ l2,
                                            const float* __restrict__ emb, int pad,
                                            const float* __restrict__ W, const float* __restrict__ bias,
                                            const float* __restrict__ hsrc, float* __restrict__ out)
{
  __shared__ float Z[8][300];
  int tx = threadIdx.x, ty = threadIdx.y;
  int t = ty * 64 + tx;
  int colbase = blockIdx.y * 8;
  for (int c = 0; c < 8; ++c) {
    int gcol = colbase + c;
    if (gcol < TC) {
      if (hsrc) {
        for (int k = t; k < 300; k += 256) Z[c][k] = hsrc[(size_t)gcol * 300 + k];
      } else {
        int tr = gcol >= NN;
        int node = gcol - tr * NN;
        const int* L = tr ? l2 : l1;
        const int* S = tr ? sent2 : sent1;
        int tok = (L[node] < 0) ? S[node] : pad;
        const float* e = emb + (size_t)tok * 300;
        for (int k = t; k < 300; k += 256) Z[c][k] = e[k];
      }
    } else {
      for (int k = t; k < 300; k += 256) Z[c][k] = 0.f;
    }
  }
  __syncthreads();
  int r = blockIdx.x * 64 + tx;
  if (r < 1200) {
    float a0 = 0.f, a1 = 0.f;
    const float* wp = W + (size_t)r * 300;
    for (int k = 0; k < 300; k += 4) {
      float4 wv = *(const float4*)(wp + k);
      float4 z0 = *(const float4*)(&Z[ty][k]);
      float4 z1 = *(const float4*)(&Z[ty + 4][k]);
      a0 += wv.x*z0.x + wv.y*z0.y + wv.z*z0.z + wv.w*z0.w;
      a1 += wv.x*z1.x + wv.y*z1.y + wv.z*z1.z + wv.w*z1.w;
    }
    float b = bias[r];
    int g0 = colbase + ty, g1 = colbase + ty + 4;
    if (g0 < TC) out[(size_t)g0 * 1200 + r] = a0 + b;
    if (g1 < TC) out[(size_t)g1 * 1200 + r] = a1 + b;
  }
}

// ---------------- attention: one block per output row (beta rows then alpha rows) ----------------
__global__ __launch_bounds__(256) void k_attn(const float* __restrict__ Henc, float* __restrict__ ab)
{
  __shared__ float q[300];
  __shared__ float pr[NN];
  __shared__ float red[256];
  int b = blockIdx.x, t = threadIdx.x;
  int dir = b >= NN;
  int i = b - dir * NN;
  const float* Ss = Henc + (dir ? NN * 300 : 0);
  const float* So = Henc + (dir ? 0 : NN * 300);
  for (int k = t; k < 300; k += 256) q[k] = Ss[(size_t)i * 300 + k];
  __syncthreads();
  float v = -1e30f;
  if (t < NN) {
    const float* row = So + (size_t)t * 300;
    float a = 0.f;
    for (int k = 0; k < 300; k += 4) {
      float4 rv = *(const float4*)(row + k);
      float4 qv = *(const float4*)(&q[k]);
      a += rv.x*qv.x + rv.y*qv.y + rv.z*qv.z + rv.w*qv.w;
    }
    pr[t] = a;
    v = a;
  }
  red[t] = v;
  __syncthreads();
  for (int s = 128; s > 0; s >>= 1) { if (t < s) red[t] = fmaxf(red[t], red[t + s]); __syncthreads(); }
  float mx = red[0];
  __syncthreads();
  float e = 0.f;
  if (t < NN) { e = expf(pr[t] - mx); pr[t] = e; }
  red[t] = e;
  __syncthreads();
  for (int s = 128; s > 0; s >>= 1) { if (t < s) red[t] += red[t + s]; __syncthreads(); }
  float inv = 1.0f / red[0];
  __syncthreads();
  for (int m = t; m < 300; m += 256) {
    float a = 0.f;
    for (int j = 0; j < NN; ++j) a += pr[j] * So[(size_t)j * 300 + m];
    ab[(size_t)b * 300 + m] = a * inv;
  }
}

// ---------------- compare h: h = relu(Wc @ [s,a,s-a,s*a] + bc). R=300, K=1200 ----------------
__global__ __launch_bounds__(256) void k_hcmp(const float* __restrict__ Henc, const float* __restrict__ ab,
                                              const float* __restrict__ Wc, const float* __restrict__ bc,
                                              float* __restrict__ hc)
{
  __shared__ float Z[8][1200];
  int tx = threadIdx.x, ty = threadIdx.y;
  int t = ty * 64 + tx;
  int colbase = blockIdx.y * 8;
  for (int c = 0; c < 8; ++c) {
    int gcol = colbase + c;
    if (gcol < TC) {
      const float* sp = Henc + (size_t)gcol * 300;
      const float* ap = ab + (size_t)gcol * 300;
      for (int k = t; k < 1200; k += 256) {
        int sel = k >= 900 ? 3 : (k >= 600 ? 2 : (k >= 300 ? 1 : 0));
        int kk = k - sel * 300;
        float s = sp[kk], a = ap[kk];
        Z[c][k] = sel == 0 ? s : sel == 1 ? a : sel == 2 ? (s - a) : (s * a);
      }
    } else {
      for (int k = t; k < 1200; k += 256) Z[c][k] = 0.f;
    }
  }
  __syncthreads();
  int r = blockIdx.x * 64 + tx;
  if (r < 300) {
    float a0 = 0.f, a1 = 0.f;
    const float* wp = Wc + (size_t)r * 1200;
    for (int k = 0; k < 1200; k += 4) {
      float4 wv = *(const float4*)(wp + k);
      float4 z0 = *(const float4*)(&Z[ty][k]);
      float4 z1 = *(const float4*)(&Z[ty + 4][k]);
      a0 += wv.x*z0.x + wv.y*z0.y + wv.z*z0.z + wv.w*z0.w;
      a1 += wv.x*z1.x + wv.y*z1.y + wv.z*z1.z + wv.w*z1.w;
    }
    float b = bc[r];
    int g0 = colbase + ty, g1 = colbase + ty + 4;
    if (g0 < TC) hc[(size_t)g0 * 300 + r] = fmaxf(a0 + b, 0.f);
    if (g1 < TC) hc[(size_t)g1 * 300 + r] = fmaxf(a1 + b, 0.f);
  }
}

// ---------------- aggregate: mean/max over nodes per tree ----------------
__global__ __launch_bounds__(256) void k_agg(const float* __restrict__ Hcmp, float* __restrict__ agg)
{
  int tr = blockIdx.x, t = threadIdx.x;
  for (int m = t; m < 300; m += 256) {
    float s = 0.f, mx = -1e30f;
    const float* hp = Hcmp + (size_t)tr * NN * 300 + m;
    for (int n = 0; n < NN; ++n) { float v = hp[(size_t)n * 300]; s += v; mx = fmaxf(mx, v); }
    agg[tr * 600 + m] = s / 255.0f;
    agg[tr * 600 + 300 + m] = mx;
  }
}

// ---------------- MLP head ----------------
__global__ __launch_bounds__(512) void k_mlp(const float* __restrict__ agg,
                                             const float* __restrict__ Wa1, const float* __restrict__ ba1,
                                             const float* __restrict__ Wa2, const float* __restrict__ ba2,
                                             float* __restrict__ out)
{
  __shared__ float a_s[1200];
  __shared__ float hid[300];
  int t = threadIdx.x;
  for (int k = t; k < 1200; k += 512) a_s[k] = agg[k];
  __syncthreads();
  for (int h = t; h < 300; h += 512) {
    float acc = ba1[h];
    const float* wp = Wa1 + (size_t)h * 1200;
    for (int k = 0; k < 1200; k += 4) {
      float4 wv = *(const float4*)(wp + k);
      float4 av = *(const float4*)(&a_s[k]);
      acc += wv.x*av.x + wv.y*av.y + wv.z*av.z + wv.w*av.w;
    }
    hid[h] = fmaxf(acc, 0.f);
  }
  __syncthreads();
  if (t < 192) {
    int c = t >> 6, lane = t & 63;
    float a = 0.f;
    for (int k = lane; k < 300; k += 64) a += Wa2[c * 300 + k] * hid[k];
    for (int off = 32; off > 0; off >>= 1) a += __shfl_down(a, off);
    if (lane == 0) out[c] = a + ba2[c];
  }
}

extern "C" void kernel_launch(void* const* d_in, const int* in_sizes, int n_in,
                              void* d_out, int out_size, void* d_ws, size_t ws_size,
                              hipStream_t stream)
{
  const int*   sent1 = (const int*)d_in[0];
  const int*   sent2 = (const int*)d_in[1];
  const int*   l1    = (const int*)d_in[2];
  const int*   r1    = (const int*)d_in[3];
  const int*   l2    = (const int*)d_in[4];
  const int*   r2    = (const int*)d_in[5];
  const float* emb   = (const float*)d_in[6];
  const float* Wx_i  = (const float*)d_in[7];
  const float* bx_i  = (const float*)d_in[8];
  const float* Wl_i  = (const float*)d_in[9];
  const float* Wr_i  = (const float*)d_in[10];
  const float* Wx_c  = (const float*)d_in[11];
  const float* bx_c  = (const float*)d_in[12];
  const float* Wl_c  = (const float*)d_in[13];
  const float* Wr_c  = (const float*)d_in[14];
  const float* Wc    = (const float*)d_in[15];
  const float* bc    = (const float*)d_in[16];
  const float* Wa1   = (const float*)d_in[17];
  const float* ba1   = (const float*)d_in[18];
  const float* Wa2   = (const float*)d_in[19];
  const float* ba2   = (const float*)d_in[20];
  int V = in_sizes[6] / 300;
  int pad = V - 1;

  char* w = (char*)d_ws;
  unsigned* bar1 = (unsigned*)w;              // flags[300] + gate, stage 1
  unsigned* bar2 = (unsigned*)(w + 2048);     // flags[300] + gate, stage 2
  int* cnt   = (int*)(w + 4096);              // 16 ints
  int* lists = (int*)(w + 4160);              // 16*256 ints
  float* xg   = (float*)(w + 20544);          // [510][1200]
  float* Henc = xg + 612000;                  // [510][300]
  float* Hcmp = Henc + 153000;                // [510][300]
  float* C    = Hcmp + 153000;                // [510][300] (shared across stages)
  float* ab   = C + 153000;                   // [510][300] beta rows then alpha rows
  float* hc   = ab + 153000;                  // [510][300]
  float* agg  = hc + 153000;                  // [1200]

  hipMemsetAsync((void*)bar1, 0, 4096, stream);
  k_setup<<<1, 512, 0, stream>>>(l1, r1, l2, r2, lists, cnt);

  dim3 blk(64, 4);

  // encode stage
  k_xg<<<dim3(19, 64), blk, 0, stream>>>(sent1, sent2, l1, l2, emb, pad, Wx_i, bx_i, nullptr, xg);
  {
    void* args[] = {(void*)&l1, (void*)&r1, (void*)&l2, (void*)&r2,
                    (void*)&Wl_i, (void*)&Wr_i, (void*)&xg,
                    (void*)&Henc, (void*)&C, (void*)&lists, (void*)&cnt, (void*)&bar1};
    hipLaunchCooperativeKernel((void*)k_tree, dim3(NBLK), dim3(256), args, 0, stream);
  }

  // attention
  k_attn<<<TC, 256, 0, stream>>>(Henc, ab);

  // compare stage
  k_hcmp<<<dim3(5, 64), blk, 0, stream>>>(Henc, ab, Wc, bc, hc);
  k_xg<<<dim3(19, 64), blk, 0, stream>>>(sent1, sent2, l1, l2, emb, pad, Wx_c, bx_c, hc, xg);
  {
    void* args[] = {(void*)&l1, (void*)&r1, (void*)&l2, (void*)&r2,
                    (void*)&Wl_c, (void*)&Wr_c, (void*)&xg,
                    (void*)&Hcmp, (void*)&C, (void*)&lists, (void*)&cnt, (void*)&bar2};
    hipLaunchCooperativeKernel((void*)k_tree, dim3(NBLK), dim3(256), args, 0, stream);
  }

  // head
  k_agg<<<2, 256, 0, stream>>>(Hcmp, agg);
  k_mlp<<<1, 512, 0, stream>>>(agg, Wa1, ba1, Wa2, ba2, (float*)d_out);
}

// Round 5
// 503.795 us; speedup vs baseline: 2.7459x; 1.0931x over previous
//
#include <hip/hip_runtime.h>
#include <math.h>

#define NN 255
#define MM 300
#define TC 510    // total columns = 2 trees * 255 nodes
#define NBLK 300  // cooperative grid size
#define CHUNK 16  // nodes per LDS chunk in k_tree
#define HTLD 512  // leading dim of transposed H

__device__ __forceinline__ float sigm(float x) { return 1.0f / (1.0f + expf(-x)); }

// relaxed agent-scope accessors: coherent at the device point, no cache flushes
__device__ __forceinline__ float aload(const float* p) {
  return __hip_atomic_load(p, __ATOMIC_RELAXED, __HIP_MEMORY_SCOPE_AGENT);
}
__device__ __forceinline__ void astore(float* p, float v) {
  __hip_atomic_store(p, v, __ATOMIC_RELAXED, __HIP_MEMORY_SCOPE_AGENT);
}

// gate a leaf node purely from its xg row (children are zero)
__device__ __forceinline__ void leaf_gate(const float* __restrict__ xgp, int m, float& c, float& h) {
  float x0 = xgp[m], x1 = xgp[300 + m], x3 = xgp[900 + m];
  float u  = tanhf(x0);
  float ig = sigm(x1);
  c = ig * u;
  h = sigm(x3) * tanhf(c);
}

// Contention-free grid barrier: per-block flag (plain relaxed store, no RMW),
// block 0 wave 0 scans flags and opens a monotonic gate.
__device__ __forceinline__ void gsync(unsigned* flags, unsigned phase) {
  asm volatile("s_waitcnt vmcnt(0)" ::: "memory");
  __syncthreads();
  unsigned* gate = flags + NBLK;
  if (blockIdx.x == 0) {
    if (threadIdx.x < 64) {
      for (;;) {
        unsigned mn = phase;
        for (int i = 1 + (int)threadIdx.x; i < NBLK; i += 64)
          mn = min(mn, __hip_atomic_load(&flags[i], __ATOMIC_RELAXED, __HIP_MEMORY_SCOPE_AGENT));
        if (__all(mn >= phase)) break;
        __builtin_amdgcn_s_sleep(2);
      }
      if (threadIdx.x == 0)
        __hip_atomic_store(gate, phase, __ATOMIC_RELAXED, __HIP_MEMORY_SCOPE_AGENT);
    }
  } else {
    if (threadIdx.x == 0) {
      __hip_atomic_store(&flags[blockIdx.x], phase, __ATOMIC_RELAXED, __HIP_MEMORY_SCOPE_AGENT);
      while (__hip_atomic_load(gate, __ATOMIC_RELAXED, __HIP_MEMORY_SCOPE_AGENT) < phase)
        __builtin_amdgcn_s_sleep(2);
    }
  }
  __syncthreads();
}

// ---------------- setup: per-level node lists as int4{gi, gl, gr, 0} ----------------
__global__ __launch_bounds__(512) void k_setup(const int* __restrict__ l1, const int* __restrict__ r1,
                                               const int* __restrict__ l2, const int* __restrict__ r2,
                                               int4* __restrict__ lists2, int* __restrict__ cnt)
{
  __shared__ int lv[TC];
  __shared__ int cs[16];
  int t = threadIdx.x;
  if (t < TC) lv[t] = 0;
  if (t < 16) cs[t] = 0;
  __syncthreads();
  for (int it = 0; it < 12; ++it) {
    int nv = 0;
    if (t < TC) {
      int tr = t >= NN;
      int i  = t - tr * NN;
      const int* L = tr ? l2 : l1;
      const int* R = tr ? r2 : r1;
      int l = L[i], r = R[i];
      nv = (l < 0) ? 0 : 1 + max(lv[tr * NN + l], lv[tr * NN + r]);
    }
    __syncthreads();
    if (t < TC) lv[t] = nv;
    __syncthreads();
  }
  if (t < TC) {
    int tr = t >= NN;
    int i  = t - tr * NN;
    int v  = min(lv[t], 15);
    int pos = atomicAdd(&cs[v], 1);
    int l = (tr ? l2 : l1)[i], r = (tr ? r2 : r1)[i];
    lists2[v * 256 + pos] = make_int4(tr * NN + i, tr * NN + max(l, 0), tr * NN + max(r, 0), 0);
  }
  __syncthreads();
  if (t < 16) cnt[t] = cs[t];
}

// ---------------- persistent cooperative tree-LSTM (one launch per stage) ----------------
// 300 blocks x 256 threads (4 wave-teams; team owns output row m = mblk*4+team).
// blockIdx = grp*75 + mblk: 4 node-group partitions x 75 m-blocks.
// Weights in registers; H staging is reg-staged with unrolled independent loads.
__global__ __launch_bounds__(256, 2) void k_tree(
    const int* __restrict__ l1, const int* __restrict__ l2,
    const float* __restrict__ Wl, const float* __restrict__ Wr,
    const float* __restrict__ xg,
    float* __restrict__ H, float* __restrict__ C, float* __restrict__ HT,
    const int4* __restrict__ lists2, const int* __restrict__ cnt,
    unsigned* __restrict__ bar)
{
  __shared__ float Hs[CHUNK][2][320];
  __shared__ float Cs[CHUNK][4][2];
  __shared__ float Xs[CHUNK][4][4];
  __shared__ int4 nfo[288];
  __shared__ int lvoff[9];

  const int tid  = threadIdx.x;
  const int lane = tid & 63;
  const int team = tid >> 6;
  const int mblk = blockIdx.x % 75;
  const int grp  = blockIdx.x / 75;
  const int m    = mblk * 4 + team;

  // ---- one-time: weight slice into registers (K interleaved by lane) ----
  float wl[5][5], wr[5][5];
  #pragma unroll
  for (int g = 0; g < 5; ++g) {
    #pragma unroll
    for (int j = 0; j < 5; ++j) {
      int d = j * 64 + lane;
      size_t o = ((size_t)g * 300 + m) * 300 + d;
      wl[g][j] = (d < 300) ? Wl[o] : 0.f;
      wr[g][j] = (d < 300) ? Wr[o] : 0.f;
    }
  }

  // ---- one-time: node metadata into LDS ----
  if (tid == 0) { int o = 0; for (int lv = 1; lv <= 7; ++lv) { lvoff[lv] = o; o += cnt[lv]; } }
  __syncthreads();
  for (int lv = 1; lv <= 7; ++lv)
    for (int i = tid; i < cnt[lv]; i += 256)
      nfo[lvoff[lv] + i] = lists2[lv * 256 + i];

  // ---- phase 0: all leaves' H,C (+ transposed H) ----
  for (int e = blockIdx.x * 256 + tid; e < TC * 300; e += 256 * NBLK) {
    int gi = e / 300;
    int mm = e - gi * 300;
    int tr = gi >= NN;
    int node = gi - tr * NN;
    if ((tr ? l2 : l1)[node] < 0) {
      float c, h;
      leaf_gate(xg + (size_t)gi * 1200, mm, c, h);
      astore(&C[(size_t)gi * 300 + mm], c);
      astore(&H[(size_t)gi * 300 + mm], h);
      astore(&HT[(size_t)mm * HTLD + gi], h);
    }
  }
  gsync(bar, 1);   // also publishes nfo/lvoff to the whole block

  // ---- levels 1..7 ----
  for (int lv = 1; lv <= 7; ++lv) {
    int nodes = cnt[lv];
    int npg = (nodes + 3) >> 2;
    int n0 = grp * npg;
    int n1 = min(nodes, n0 + npg);
    for (int nb = n0; nb < n1; nb += CHUNK) {
      int nch = min(CHUNK, n1 - nb);
      int base = lvoff[lv] + nb;
      __syncthreads();   // previous chunk done with LDS

      // -- Hs staging: per wave, 2 passes x 2 nodes, reg-staged unrolled loads --
      #pragma unroll
      for (int p = 0; p < 2; ++p) {
        int niA = team + p * 8;
        int niB = niA + 4;
        bool vA = niA < nch, vB = niB < nch;
        int4 na = vA ? nfo[base + niA] : make_int4(0, 0, 0, 0);
        int4 nb4 = vB ? nfo[base + niB] : make_int4(0, 0, 0, 0);
        float bA0, bA1, bA2, bA3, bA4, bA5, bA6, bA7, bA8, bA9;
        float bB0, bB1, bB2, bB3, bB4, bB5, bB6, bB7, bB8, bB9;
        #define LD(side_ptr, d, ok) ((ok) ? aload(&H[(size_t)(side_ptr) * 300 + (d)]) : 0.f)
        {
          int d0 = lane, d1 = 64 + lane, d2 = 128 + lane, d3 = 192 + lane, d4 = 256 + lane;
          bool i4 = d4 < 300;
          bA0 = LD(na.y, d0, vA); bA1 = LD(na.y, d1, vA); bA2 = LD(na.y, d2, vA);
          bA3 = LD(na.y, d3, vA); bA4 = LD(na.y, d4, vA && i4);
          bA5 = LD(na.z, d0, vA); bA6 = LD(na.z, d1, vA); bA7 = LD(na.z, d2, vA);
          bA8 = LD(na.z, d3, vA); bA9 = LD(na.z, d4, vA && i4);
          bB0 = LD(nb4.y, d0, vB); bB1 = LD(nb4.y, d1, vB); bB2 = LD(nb4.y, d2, vB);
          bB3 = LD(nb4.y, d3, vB); bB4 = LD(nb4.y, d4, vB && i4);
          bB5 = LD(nb4.z, d0, vB); bB6 = LD(nb4.z, d1, vB); bB7 = LD(nb4.z, d2, vB);
          bB8 = LD(nb4.z, d3, vB); bB9 = LD(nb4.z, d4, vB && i4);
          if (vA) {
            Hs[niA][0][d0] = bA0; Hs[niA][0][d1] = bA1; Hs[niA][0][d2] = bA2;
            Hs[niA][0][d3] = bA3; Hs[niA][0][d4] = bA4;
            Hs[niA][1][d0] = bA5; Hs[niA][1][d1] = bA6; Hs[niA][1][d2] = bA7;
            Hs[niA][1][d3] = bA8; Hs[niA][1][d4] = bA9;
          }
          if (vB) {
            Hs[niB][0][d0] = bB0; Hs[niB][0][d1] = bB1; Hs[niB][0][d2] = bB2;
            Hs[niB][0][d3] = bB3; Hs[niB][0][d4] = bB4;
            Hs[niB][1][d0] = bB5; Hs[niB][1][d1] = bB6; Hs[niB][1][d2] = bB7;
            Hs[niB][1][d3] = bB8; Hs[niB][1][d4] = bB9;
          }
        }
        #undef LD
      }
      // -- Cs prefetch (children C for the gating tails), 1 load/thread --
      if (tid < 128) {
        int ni = tid >> 3, tm = (tid >> 1) & 3, side = tid & 1;
        if (ni < nch) {
          int4 nn = nfo[base + ni];
          int child = side ? nn.z : nn.y;
          Cs[ni][tm][side] = aload(&C[(size_t)child * 300 + mblk * 4 + tm]);
        }
      }
      // -- Xs prefetch (xg gate terms), 1 load/thread --
      {
        int ni = tid >> 4, tm = (tid >> 2) & 3, g = tid & 3;
        if (ni < nch) {
          int4 nn = nfo[base + ni];
          Xs[ni][tm][g] = xg[(size_t)nn.x * 1200 + g * 300 + mblk * 4 + tm];
        }
      }
      __syncthreads();

      #pragma unroll 2
      for (int ni = 0; ni < nch; ++ni) {
        float p0 = 0.f, p1 = 0.f, p2 = 0.f, p3 = 0.f, p4 = 0.f;
        #pragma unroll
        for (int j = 0; j < 5; ++j) {
          float hl = Hs[ni][0][j * 64 + lane];
          float hr = Hs[ni][1][j * 64 + lane];
          p0 += wl[0][j] * hl + wr[0][j] * hr;
          p1 += wl[1][j] * hl + wr[1][j] * hr;
          p2 += wl[2][j] * hl + wr[2][j] * hr;
          p3 += wl[3][j] * hl + wr[3][j] * hr;
          p4 += wl[4][j] * hl + wr[4][j] * hr;
        }
        #pragma unroll
        for (int off = 32; off; off >>= 1) {
          p0 += __shfl_xor(p0, off);
          p1 += __shfl_xor(p1, off);
          p2 += __shfl_xor(p2, off);
          p3 += __shfl_xor(p3, off);
          p4 += __shfl_xor(p4, off);
        }
        if (lane == 0) {
          int4 nn = nfo[base + ni];
          int gi = nn.x;
          float lc = Cs[ni][team][0], rc = Cs[ni][team][1];
          float u  = tanhf(Xs[ni][team][0] + p0);
          float ig = sigm (Xs[ni][team][1] + p1);
          float lf = sigm (Xs[ni][team][2] + p2);
          float rf = sigm (Xs[ni][team][2] + p3);   // fx shared for both forgets
          float o  = sigm (Xs[ni][team][3] + p4);
          float cc = ig * u + lf * lc + rf * rc;
          float hv = o * tanhf(cc);
          astore(&C[(size_t)gi * 300 + m], cc);
          astore(&H[(size_t)gi * 300 + m], hv);
          astore(&HT[(size_t)m * HTLD + gi], hv);
        }
      }
    }
    if (lv < 7) gsync(bar, 1 + lv);
  }
}

// ---------------- xg GEMM: out[col][r] = bias[r] + sum_d W[r][d] * Z[col][d] ----------------
__global__ __launch_bounds__(256) void k_xg(const int* __restrict__ sent1, const int* __restrict__ sent2,
                                            const int* __restrict__ l1, const int* __restrict__ l2,
                                            const float* __restrict__ emb, int pad,
                                            const float* __restrict__ W, const float* __restrict__ bias,
                                            const float* __restrict__ hsrc, float* __restrict__ out)
{
  __shared__ float Z[8][300];
  int tx = threadIdx.x, ty = threadIdx.y;
  int t = ty * 64 + tx;
  int colbase = blockIdx.y * 8;
  for (int c = 0; c < 8; ++c) {
    int gcol = colbase + c;
    if (gcol < TC) {
      if (hsrc) {
        for (int k = t; k < 300; k += 256) Z[c][k] = hsrc[(size_t)gcol * 300 + k];
      } else {
        int tr = gcol >= NN;
        int node = gcol - tr * NN;
        const int* L = tr ? l2 : l1;
        const int* S = tr ? sent2 : sent1;
        int tok = (L[node] < 0) ? S[node] : pad;
        const float* e = emb + (size_t)tok * 300;
        for (int k = t; k < 300; k += 256) Z[c][k] = e[k];
      }
    } else {
      for (int k = t; k < 300; k += 256) Z[c][k] = 0.f;
    }
  }
  __syncthreads();
  int r = blockIdx.x * 64 + tx;
  if (r < 1200) {
    float a0 = 0.f, a1 = 0.f;
    const float* wp = W + (size_t)r * 300;
    for (int k = 0; k < 300; k += 4) {
      float4 wv = *(const float4*)(wp + k);
      float4 z0 = *(const float4*)(&Z[ty][k]);
      float4 z1 = *(const float4*)(&Z[ty + 4][k]);
      a0 += wv.x*z0.x + wv.y*z0.y + wv.z*z0.z + wv.w*z0.w;
      a1 += wv.x*z1.x + wv.y*z1.y + wv.z*z1.z + wv.w*z1.w;
    }
    float b = bias[r];
    int g0 = colbase + ty, g1 = colbase + ty + 4;
    if (g0 < TC) out[(size_t)g0 * 1200 + r] = a0 + b;
    if (g1 < TC) out[(size_t)g1 * 1200 + r] = a1 + b;
  }
}

// ---------------- attention: one block per output row; scores via transposed H ----------------
__global__ __launch_bounds__(256) void k_attn(const float* __restrict__ H, const float* __restrict__ HT,
                                              float* __restrict__ ab)
{
  __shared__ float q[300];
  __shared__ float pr[NN];
  __shared__ float red[256];
  int b = blockIdx.x, t = threadIdx.x;
  int dir = b >= NN;
  int i = b - dir * NN;
  const float* Ss = H + (dir ? NN * 300 : 0);
  const float* So = H + (dir ? 0 : NN * 300);
  int oppb = dir ? 0 : NN;
  for (int k = t; k < 300; k += 256) q[k] = Ss[(size_t)i * 300 + k];
  __syncthreads();
  float v = -1e30f;
  if (t < NN) {
    float a = 0.f;
    const float* hp = HT + oppb + t;
    #pragma unroll 4
    for (int k = 0; k < 300; ++k) a += q[k] * hp[(size_t)k * HTLD];
    pr[t] = a;
    v = a;
  }
  red[t] = v;
  __syncthreads();
  for (int s = 128; s > 0; s >>= 1) { if (t < s) red[t] = fmaxf(red[t], red[t + s]); __syncthreads(); }
  float mx = red[0];
  __syncthreads();
  float e = 0.f;
  if (t < NN) { e = expf(pr[t] - mx); pr[t] = e; }
  red[t] = e;
  __syncthreads();
  for (int s = 128; s > 0; s >>= 1) { if (t < s) red[t] += red[t + s]; __syncthreads(); }
  float inv = 1.0f / red[0];
  __syncthreads();
  for (int m = t; m < 300; m += 256) {
    float a = 0.f;
    for (int j = 0; j < NN; ++j) a += pr[j] * So[(size_t)j * 300 + m];
    ab[(size_t)b * 300 + m] = a * inv;
  }
}

// ---------------- compare h: h = relu(Wc @ [s,a,s-a,s*a] + bc). R=300, K=1200 ----------------
__global__ __launch_bounds__(256) void k_hcmp(const float* __restrict__ Henc, const float* __restrict__ ab,
                                              const float* __restrict__ Wc, const float* __restrict__ bc,
                                              float* __restrict__ hc)
{
  __shared__ float Z[8][1200];
  int tx = threadIdx.x, ty = threadIdx.y;
  int t = ty * 64 + tx;
  int colbase = blockIdx.y * 8;
  for (int c = 0; c < 8; ++c) {
    int gcol = colbase + c;
    if (gcol < TC) {
      const float* sp = Henc + (size_t)gcol * 300;
      const float* ap = ab + (size_t)gcol * 300;
      for (int k = t; k < 1200; k += 256) {
        int sel = k >= 900 ? 3 : (k >= 600 ? 2 : (k >= 300 ? 1 : 0));
        int kk = k - sel * 300;
        float s = sp[kk], a = ap[kk];
        Z[c][k] = sel == 0 ? s : sel == 1 ? a : sel == 2 ? (s - a) : (s * a);
      }
    } else {
      for (int k = t; k < 1200; k += 256) Z[c][k] = 0.f;
    }
  }
  __syncthreads();
  int r = blockIdx.x * 64 + tx;
  if (r < 300) {
    float a0 = 0.f, a1 = 0.f;
    const float* wp = Wc + (size_t)r * 1200;
    for (int k = 0; k < 1200; k += 4) {
      float4 wv = *(const float4*)(wp + k);
      float4 z0 = *(const float4*)(&Z[ty][k]);
      float4 z1 = *(const float4*)(&Z[ty + 4][k]);
      a0 += wv.x*z0.x + wv.y*z0.y + wv.z*z0.z + wv.w*z0.w;
      a1 += wv.x*z1.x + wv.y*z1.y + wv.z*z1.z + wv.w*z1.w;
    }
    float b = bc[r];
    int g0 = colbase + ty, g1 = colbase + ty + 4;
    if (g0 < TC) hc[(size_t)g0 * 300 + r] = fmaxf(a0 + b, 0.f);
    if (g1 < TC) hc[(size_t)g1 * 300 + r] = fmaxf(a1 + b, 0.f);
  }
}

// ---------------- head: mean/max aggregate (from transposed Hcmp) + MLP ----------------
__global__ __launch_bounds__(512) void k_head(const float* __restrict__ HTc,
                                              const float* __restrict__ Wa1, const float* __restrict__ ba1,
                                              const float* __restrict__ Wa2, const float* __restrict__ ba2,
                                              float* __restrict__ out)
{
  __shared__ float a_s[1200];
  __shared__ float hid[300];
  int t = threadIdx.x;
  for (int idx = t; idx < 600; idx += 512) {
    int tr = idx >= 300;
    int m = idx - tr * 300;
    const float* p = HTc + (size_t)m * HTLD + tr * NN;
    float s = 0.f, mx = -1e30f;
    for (int n = 0; n < NN; ++n) { float v = p[n]; s += v; mx = fmaxf(mx, v); }
    a_s[tr * 600 + m] = s / 255.0f;
    a_s[tr * 600 + 300 + m] = mx;
  }
  __syncthreads();
  for (int h = t; h < 300; h += 512) {
    float acc = ba1[h];
    const float* wp = Wa1 + (size_t)h * 1200;
    for (int k = 0; k < 1200; k += 4) {
      float4 wv = *(const float4*)(wp + k);
      float4 av = *(const float4*)(&a_s[k]);
      acc += wv.x*av.x + wv.y*av.y + wv.z*av.z + wv.w*av.w;
    }
    hid[h] = fmaxf(acc, 0.f);
  }
  __syncthreads();
  if (t < 192) {
    int c = t >> 6, lane = t & 63;
    float a = 0.f;
    for (int k = lane; k < 300; k += 64) a += Wa2[c * 300 + k] * hid[k];
    for (int off = 32; off > 0; off >>= 1) a += __shfl_down(a, off);
    if (lane == 0) out[c] = a + ba2[c];
  }
}

extern "C" void kernel_launch(void* const* d_in, const int* in_sizes, int n_in,
                              void* d_out, int out_size, void* d_ws, size_t ws_size,
                              hipStream_t stream)
{
  const int*   sent1 = (const int*)d_in[0];
  const int*   sent2 = (const int*)d_in[1];
  const int*   l1    = (const int*)d_in[2];
  const int*   r1    = (const int*)d_in[3];
  const int*   l2    = (const int*)d_in[4];
  const int*   r2    = (const int*)d_in[5];
  const float* emb   = (const float*)d_in[6];
  const float* Wx_i  = (const float*)d_in[7];
  const float* bx_i  = (const float*)d_in[8];
  const float* Wl_i  = (const float*)d_in[9];
  const float* Wr_i  = (const float*)d_in[10];
  const float* Wx_c  = (const float*)d_in[11];
  const float* bx_c  = (const float*)d_in[12];
  const float* Wl_c  = (const float*)d_in[13];
  const float* Wr_c  = (const float*)d_in[14];
  const float* Wc    = (const float*)d_in[15];
  const float* bc    = (const float*)d_in[16];
  const float* Wa1   = (const float*)d_in[17];
  const float* ba1   = (const float*)d_in[18];
  const float* Wa2   = (const float*)d_in[19];
  const float* ba2   = (const float*)d_in[20];
  int V = in_sizes[6] / 300;
  int pad = V - 1;

  char* w = (char*)d_ws;
  unsigned* bar1 = (unsigned*)w;              // flags[300] + gate, stage 1
  unsigned* bar2 = (unsigned*)(w + 2048);     // flags[300] + gate, stage 2
  int* cnt     = (int*)(w + 4096);            // 16 ints
  int4* lists2 = (int4*)(w + 4160);           // 16*256 int4 = 64 KB
  float* xg   = (float*)(w + 4160 + 65536);   // [510][1200]
  float* Henc = xg + 612000;                  // [510][300]
  float* Hcmp = Henc + 153000;                // [510][300]
  float* C    = Hcmp + 153000;                // [510][300] (shared across stages)
  float* ab   = C + 153000;                   // [510][300]
  float* hc   = ab + 153000;                  // [510][300]
  float* HTe  = hc + 153000;                  // [300][512] transposed Henc
  float* HTc  = HTe + 153600;                 // [300][512] transposed Hcmp

  hipMemsetAsync((void*)bar1, 0, 4096, stream);
  k_setup<<<1, 512, 0, stream>>>(l1, r1, l2, r2, lists2, cnt);

  dim3 blk(64, 4);

  // encode stage
  k_xg<<<dim3(19, 64), blk, 0, stream>>>(sent1, sent2, l1, l2, emb, pad, Wx_i, bx_i, nullptr, xg);
  {
    void* args[] = {(void*)&l1, (void*)&l2,
                    (void*)&Wl_i, (void*)&Wr_i, (void*)&xg,
                    (void*)&Henc, (void*)&C, (void*)&HTe,
                    (void*)&lists2, (void*)&cnt, (void*)&bar1};
    hipLaunchCooperativeKernel((void*)k_tree, dim3(NBLK), dim3(256), args, 0, stream);
  }

  // attention
  k_attn<<<TC, 256, 0, stream>>>(Henc, HTe, ab);

  // compare stage
  k_hcmp<<<dim3(5, 64), blk, 0, stream>>>(Henc, ab, Wc, bc, hc);
  k_xg<<<dim3(19, 64), blk, 0, stream>>>(sent1, sent2, l1, l2, emb, pad, Wx_c, bx_c, hc, xg);
  {
    void* args[] = {(void*)&l1, (void*)&l2,
                    (void*)&Wl_c, (void*)&Wr_c, (void*)&xg,
                    (void*)&Hcmp, (void*)&C, (void*)&HTc,
                    (void*)&lists2, (void*)&cnt, (void*)&bar2};
    hipLaunchCooperativeKernel((void*)k_tree, dim3(NBLK), dim3(256), args, 0, stream);
  }

  // head
  k_head<<<1, 512, 0, stream>>>(HTc, Wa1, ba1, Wa2, ba2, (float*)d_out);
}

// Round 7
// 496.029 us; speedup vs baseline: 2.7889x; 1.0157x over previous
//
#include <hip/hip_runtime.h>
#include <math.h>

#define NN 255
#define TC 510
#define HTLD 512
#define FNB 600   // fused cooperative grid (8 node-groups x 75 m-blocks)
#define FNG 8
#define FCH 12    // fused chunk (nodes per LDS staging round)
#define BNB 300   // fallback cooperative grid
#define BCH 16

typedef unsigned int uint32;

__device__ __forceinline__ float sigm(float x){ return 1.f/(1.f+expf(-x)); }

// relaxed agent-scope accessors: coherent at the device point, no cache flushes
__device__ __forceinline__ float aload(const float* p){ return __hip_atomic_load(p, __ATOMIC_RELAXED, __HIP_MEMORY_SCOPE_AGENT); }
__device__ __forceinline__ void astore(float* p, float v){ __hip_atomic_store(p, v, __ATOMIC_RELAXED, __HIP_MEMORY_SCOPE_AGENT); }
__device__ __forceinline__ uint32 aloadu(const uint32* p){ return __hip_atomic_load(p, __ATOMIC_RELAXED, __HIP_MEMORY_SCOPE_AGENT); }
__device__ __forceinline__ void astoreu(uint32* p, uint32 v){ __hip_atomic_store(p, v, __ATOMIC_RELAXED, __HIP_MEMORY_SCOPE_AGENT); }

__device__ __forceinline__ void leaf_gate(const float* __restrict__ xgp, int m, float& c, float& h){
  float x0 = xgp[m], x1 = xgp[300+m], x3 = xgp[900+m];
  float u = tanhf(x0), ig = sigm(x1);
  c = ig * u;
  h = sigm(x3) * tanhf(c);
}

// Contention-free grid barrier (monotonic phase): per-block flag store, block 0
// wave 0 scans flags, opens a gate. vmcnt drain publishes prior sc1 stores.
template<int NB>
__device__ __forceinline__ void gsync(uint32* flags, uint32 phase){
  asm volatile("s_waitcnt vmcnt(0)" ::: "memory");
  __syncthreads();
  uint32* gate = flags + NB;
  if (blockIdx.x == 0){
    if (threadIdx.x < 64){
      for(;;){
        uint32 mn = phase;
        for (int i = 1 + (int)threadIdx.x; i < NB; i += 64)
          mn = min(mn, aloadu(&flags[i]));
        if (__all(mn >= phase)) break;
        __builtin_amdgcn_s_sleep(2);
      }
      if (threadIdx.x == 0) astoreu(gate, phase);
    }
  } else {
    if (threadIdx.x == 0){
      astoreu(&flags[blockIdx.x], phase);
      while (aloadu(gate) < phase) __builtin_amdgcn_s_sleep(2);
    }
  }
  __syncthreads();
}

// ====================== FUSED: the whole ESIM forward in one kernel ======================
// 600 blocks x 256 threads; LDS ~34 KB; __launch_bounds__(256,4) caps VGPR<=128
// -> 4 blocks/CU by construction -> 1024 co-resident >= 600 grid (always launchable).
__global__ __launch_bounds__(256, 4) void k_all(
  const int* __restrict__ sent1, const int* __restrict__ sent2,
  const int* __restrict__ l1, const int* __restrict__ r1,
  const int* __restrict__ l2, const int* __restrict__ r2,
  const float* __restrict__ emb, int pad,
  const float* __restrict__ Wx_i, const float* __restrict__ bx_i,
  const float* __restrict__ Wl_i, const float* __restrict__ Wr_i,
  const float* __restrict__ Wx_c, const float* __restrict__ bx_c,
  const float* __restrict__ Wl_c, const float* __restrict__ Wr_c,
  const float* __restrict__ Wcm, const float* __restrict__ bcm,
  const float* __restrict__ Wa1, const float* __restrict__ ba1,
  const float* __restrict__ Wa2, const float* __restrict__ ba2,
  float* __restrict__ out,
  float* __restrict__ xg_e, float* __restrict__ xg_c,
  float* __restrict__ H, float* __restrict__ C,
  float* __restrict__ ab, float* __restrict__ hc,
  float* __restrict__ HT, float* __restrict__ agg,
  uint32* __restrict__ lists, uint32* __restrict__ cntg,
  uint32* __restrict__ bar)
{
  __shared__ float ubuf[7680];           // 30720 B multipurpose (Hs / Z / attn / head / setup)
  __shared__ float Cs[FCH][4][2];
  __shared__ float Xs[FCH][4][4];
  __shared__ uint32 nfo_s[256];
  __shared__ int lvoff_s[9];
  __shared__ int cnt_s[16];
  __shared__ float red_s[256];

  const int b = blockIdx.x, tid = threadIdx.x;
  const int lane = tid & 63, team = tid >> 6;
  const int mblk = b % 75, grp = b / 75;
  const int m = mblk * 4 + team;
  int ph = 0;

  // ---- xg GEMM tiles: out[col][r] = bias[r] + W[r]·Z[col] (R=1200,K=300; 19x64 tiles, 8 cols) ----
  auto xg_tiles = [&](const float* W, const float* bias, const float* hsrc,
                      float* outp, int t0, int stride){
    float (*Z)[300] = (float(*)[300])ubuf;
    for (int t = t0; t < 1216; t += stride){
      int rb = t % 19, cb = t / 19;
      int colbase = cb * 8;
      __syncthreads();
      for (int k = tid; k < 2400; k += 256){
        int c = k / 300, d = k - c * 300;
        int gcol = colbase + c;
        float v = 0.f;
        if (gcol < TC){
          if (hsrc) v = hsrc[(size_t)gcol * 300 + d];
          else {
            int tr = gcol >= NN, node = gcol - tr * NN;
            int tok = ((tr ? l2 : l1)[node] < 0) ? (tr ? sent2 : sent1)[node] : pad;
            v = emb[(size_t)tok * 300 + d];
          }
        }
        Z[c][d] = v;
      }
      __syncthreads();
      int r = rb * 64 + lane;
      if (r < 1200){
        float a0 = 0.f, a1 = 0.f;
        const float* wp = W + (size_t)r * 300;
        for (int k = 0; k < 300; k += 4){
          float4 wv = *(const float4*)(wp + k);
          float4 z0 = *(const float4*)(&Z[team][k]);
          float4 z1 = *(const float4*)(&Z[team + 4][k]);
          a0 += wv.x*z0.x + wv.y*z0.y + wv.z*z0.z + wv.w*z0.w;
          a1 += wv.x*z1.x + wv.y*z1.y + wv.z*z1.z + wv.w*z1.w;
        }
        float bb = bias[r];
        int g0 = colbase + team, g1 = g0 + 4;
        if (g0 < TC) astore(&outp[(size_t)g0 * 1200 + r], a0 + bb);
        if (g1 < TC) astore(&outp[(size_t)g1 * 1200 + r], a1 + bb);
      }
    }
  };

  // ======== phase 0: setup (block 0)  ∥  encode-xg tiles (other blocks) ========
  if (b == 0){
    int* lv = (int*)ubuf;
    for (int i = tid; i < TC; i += 256) lv[i] = 0;
    if (tid < 16) cnt_s[tid] = 0;
    __syncthreads();
    for (int it = 0; it < 12; ++it){
      int nv0 = 0, nv1 = 0;
      {
        int i = tid;
        int tr = i >= NN, node = i - tr * NN;
        int l = (tr ? l2 : l1)[node], r = (tr ? r2 : r1)[node];
        if (l >= 0) nv0 = 1 + max(lv[tr * NN + l], lv[tr * NN + r]);
      }
      {
        int i = tid + 256;
        if (i < TC){
          int tr = i >= NN, node = i - tr * NN;
          int l = (tr ? l2 : l1)[node], r = (tr ? r2 : r1)[node];
          if (l >= 0) nv1 = 1 + max(lv[tr * NN + l], lv[tr * NN + r]);
        }
      }
      __syncthreads();
      lv[tid] = nv0;
      if (tid + 256 < TC) lv[tid + 256] = nv1;
      __syncthreads();
    }
    for (int i = tid; i < TC; i += 256){
      int tr = i >= NN, node = i - tr * NN;
      int v = min(lv[i], 15);
      int pos = atomicAdd(&cnt_s[v], 1);
      int l = (tr ? l2 : l1)[node], r = (tr ? r2 : r1)[node];
      uint32 pk = (uint32)i | ((uint32)(tr * NN + max(l, 0)) << 10) | ((uint32)(tr * NN + max(r, 0)) << 20);
      astoreu(&lists[v * 256 + pos], pk);
    }
    __syncthreads();
    if (tid < 16) astoreu(&cntg[tid], (uint32)cnt_s[tid]);
  } else {
    xg_tiles(Wx_i, bx_i, nullptr, xg_e, b - 1, FNB - 1);
  }
  gsync<FNB>(bar, (uint32)++ph);

  // ---- level metadata into LDS (all blocks) ----
  if (tid < 16) cnt_s[tid] = (int)aloadu(&cntg[tid]);
  __syncthreads();
  if (tid == 0){
    lvoff_s[1] = 0;
    for (int lv = 2; lv <= 7; ++lv) lvoff_s[lv] = lvoff_s[lv - 1] + cnt_s[lv - 1];
  }
  __syncthreads();
  for (int lv = 1; lv <= 7; ++lv)
    for (int i = tid; i < cnt_s[lv]; i += 256)
      nfo_s[lvoff_s[lv] + i] = aloadu(&lists[lv * 256 + i]);
  __syncthreads();

  // ======== tree-LSTM stage (weights in regs, reg-staged H, per-level barrier) ========
  auto tree_stage = [&](const float* Wl, const float* Wr, const float* xgp){
    float wl[5][5], wr[5][5];
    #pragma unroll
    for (int g = 0; g < 5; ++g)
      #pragma unroll
      for (int j = 0; j < 5; ++j){
        int d = j * 64 + lane;
        size_t o = ((size_t)g * 300 + m) * 300 + d;
        wl[g][j] = (d < 300) ? Wl[o] : 0.f;
        wr[g][j] = (d < 300) ? Wr[o] : 0.f;
      }
    // leaves
    for (int e = b * 256 + tid; e < TC * 300; e += 256 * FNB){
      int gi = e / 300, mm = e - gi * 300;
      int tr = gi >= NN, node = gi - tr * NN;
      if (((tr ? l2 : l1)[node]) < 0){
        float c, h; leaf_gate(xgp + (size_t)gi * 1200, mm, c, h);
        astore(&C[(size_t)gi * 300 + mm], c);
        astore(&H[(size_t)gi * 300 + mm], h);
        astore(&HT[(size_t)mm * HTLD + gi], h);
      }
    }
    gsync<FNB>(bar, (uint32)++ph);

    float (*Hs)[2][320] = (float(*)[2][320])ubuf;
    for (int lv = 1; lv <= 7; ++lv){
      int nodes = cnt_s[lv];
      int npg = (nodes + FNG - 1) / FNG;
      int n0 = grp * npg, n1 = min(nodes, n0 + npg);
      for (int nb0 = n0; nb0 < n1; nb0 += FCH){
        int nch = min(FCH, n1 - nb0);
        int base = lvoff_s[lv] + nb0;
        __syncthreads();
        // -- Hs staging: per wave, 2 passes, reg-staged unrolled agent loads --
        #pragma unroll
        for (int p = 0; p < 2; ++p){
          int niA = team + p * 8, niB = niA + 4;
          bool vA = niA < nch, vB = niB < nch;
          uint32 na = vA ? nfo_s[base + niA] : 0u;
          uint32 nk = vB ? nfo_s[base + niB] : 0u;
          int aL = (na >> 10) & 1023, aR = (na >> 20) & 1023;
          int bL = (nk >> 10) & 1023, bR = (nk >> 20) & 1023;
          int d0 = lane, d1 = 64 + lane, d2 = 128 + lane, d3 = 192 + lane, d4 = 256 + lane;
          bool i4 = d4 < 300;
          #define LDH(ci, dd, ok) ((ok) ? aload(&H[(size_t)(ci) * 300 + (dd)]) : 0.f)
          float a0=LDH(aL,d0,vA), a1=LDH(aL,d1,vA), a2=LDH(aL,d2,vA), a3=LDH(aL,d3,vA), a4=LDH(aL,d4,vA&&i4);
          float a5=LDH(aR,d0,vA), a6=LDH(aR,d1,vA), a7=LDH(aR,d2,vA), a8=LDH(aR,d3,vA), a9=LDH(aR,d4,vA&&i4);
          float c0=LDH(bL,d0,vB), c1=LDH(bL,d1,vB), c2=LDH(bL,d2,vB), c3=LDH(bL,d3,vB), c4=LDH(bL,d4,vB&&i4);
          float c5=LDH(bR,d0,vB), c6=LDH(bR,d1,vB), c7=LDH(bR,d2,vB), c8=LDH(bR,d3,vB), c9=LDH(bR,d4,vB&&i4);
          #undef LDH
          if (vA){
            Hs[niA][0][d0]=a0; Hs[niA][0][d1]=a1; Hs[niA][0][d2]=a2; Hs[niA][0][d3]=a3; Hs[niA][0][d4]=a4;
            Hs[niA][1][d0]=a5; Hs[niA][1][d1]=a6; Hs[niA][1][d2]=a7; Hs[niA][1][d3]=a8; Hs[niA][1][d4]=a9;
          }
          if (vB){
            Hs[niB][0][d0]=c0; Hs[niB][0][d1]=c1; Hs[niB][0][d2]=c2; Hs[niB][0][d3]=c3; Hs[niB][0][d4]=c4;
            Hs[niB][1][d0]=c5; Hs[niB][1][d1]=c6; Hs[niB][1][d2]=c7; Hs[niB][1][d3]=c8; Hs[niB][1][d4]=c9;
          }
        }
        // -- Cs prefetch --
        if (tid < 128){
          int ni = tid >> 3, tm = (tid >> 1) & 3, side = tid & 1;
          if (ni < nch){
            uint32 nn = nfo_s[base + ni];
            int child = side ? ((nn >> 20) & 1023) : ((nn >> 10) & 1023);
            Cs[ni][tm][side] = aload(&C[(size_t)child * 300 + mblk * 4 + tm]);
          }
        }
        // -- Xs prefetch --
        {
          int ni = tid >> 4, tm = (tid >> 2) & 3, g = tid & 3;
          if (ni < nch){
            uint32 nn = nfo_s[base + ni];
            int gi = nn & 1023;
            Xs[ni][tm][g] = xgp[(size_t)gi * 1200 + g * 300 + mblk * 4 + tm];
          }
        }
        __syncthreads();
        #pragma unroll 2
        for (int ni = 0; ni < nch; ++ni){
          float p0 = 0.f, p1 = 0.f, p2 = 0.f, p3 = 0.f, p4 = 0.f;
          #pragma unroll
          for (int j = 0; j < 5; ++j){
            float hl = Hs[ni][0][j * 64 + lane];
            float hr = Hs[ni][1][j * 64 + lane];
            p0 += wl[0][j] * hl + wr[0][j] * hr;
            p1 += wl[1][j] * hl + wr[1][j] * hr;
            p2 += wl[2][j] * hl + wr[2][j] * hr;
            p3 += wl[3][j] * hl + wr[3][j] * hr;
            p4 += wl[4][j] * hl + wr[4][j] * hr;
          }
          #pragma unroll
          for (int off = 32; off; off >>= 1){
            p0 += __shfl_xor(p0, off); p1 += __shfl_xor(p1, off); p2 += __shfl_xor(p2, off);
            p3 += __shfl_xor(p3, off); p4 += __shfl_xor(p4, off);
          }
          if (lane == 0){
            uint32 nn = nfo_s[base + ni];
            int gi = nn & 1023;
            float lc = Cs[ni][team][0], rc = Cs[ni][team][1];
            float u  = tanhf(Xs[ni][team][0] + p0);
            float ig = sigm (Xs[ni][team][1] + p1);
            float lf = sigm (Xs[ni][team][2] + p2);
            float rf = sigm (Xs[ni][team][2] + p3);   // fx shared for both forgets
            float o  = sigm (Xs[ni][team][3] + p4);
            float cc = ig * u + lf * lc + rf * rc;
            float hv = o * tanhf(cc);
            astore(&C[(size_t)gi * 300 + m], cc);
            astore(&H[(size_t)gi * 300 + m], hv);
            astore(&HT[(size_t)m * HTLD + gi], hv);
          }
        }
      }
      gsync<FNB>(bar, (uint32)++ph);
    }
  };

  // ======== encode tree ========
  tree_stage(Wl_i, Wr_i, xg_e);

  // ======== attention ========
  {
    float* q = ubuf;
    float* pr = ubuf + 304;
    for (int row = b; row < TC; row += FNB){
      __syncthreads();
      int dir = row >= NN, i = row - dir * NN;
      const float* Ss = H + (dir ? (size_t)NN * 300 : (size_t)0);
      const float* So = H + (dir ? (size_t)0 : (size_t)NN * 300);
      int oppb = dir ? 0 : NN;
      for (int k = tid; k < 300; k += 256) q[k] = Ss[(size_t)i * 300 + k];
      __syncthreads();
      float v = -1e30f;
      if (tid < NN){
        const float* hp = HT + oppb + tid;
        float a = 0.f;
        #pragma unroll 4
        for (int k = 0; k < 300; ++k) a += q[k] * hp[(size_t)k * HTLD];
        pr[tid] = a; v = a;
      }
      red_s[tid] = v; __syncthreads();
      for (int s = 128; s; s >>= 1){ if (tid < s) red_s[tid] = fmaxf(red_s[tid], red_s[tid + s]); __syncthreads(); }
      float mx = red_s[0]; __syncthreads();
      float e = 0.f;
      if (tid < NN){ e = expf(pr[tid] - mx); pr[tid] = e; }
      red_s[tid] = e; __syncthreads();
      for (int s = 128; s; s >>= 1){ if (tid < s) red_s[tid] += red_s[tid + s]; __syncthreads(); }
      float inv = 1.f / red_s[0]; __syncthreads();
      for (int mm = tid; mm < 300; mm += 256){
        float a = 0.f;
        for (int j = 0; j < NN; ++j) a += pr[j] * So[(size_t)j * 300 + mm];
        astore(&ab[(size_t)row * 300 + mm], a * inv);
      }
    }
  }
  gsync<FNB>(bar, (uint32)++ph);

  // ======== compare h = relu(Wc·[s,a,s-a,s*a]+bc)  (5 x 85 tiles, 6 cols each) ========
  {
    float (*Z)[1200] = (float(*)[1200])ubuf;
    for (int t = b; t < 425; t += FNB){
      int rb = t % 5, cb = t / 5;
      int colbase = cb * 6;
      __syncthreads();
      for (int k = tid; k < 7200; k += 256){
        int c = k / 1200, rem = k - c * 1200;
        int gcol = colbase + c;
        float v = 0.f;
        if (gcol < TC){
          int sel = rem >= 900 ? 3 : rem >= 600 ? 2 : rem >= 300 ? 1 : 0;
          int kk = rem - sel * 300;
          float s = H[(size_t)gcol * 300 + kk], a = ab[(size_t)gcol * 300 + kk];
          v = sel == 0 ? s : sel == 1 ? a : sel == 2 ? (s - a) : (s * a);
        }
        Z[c][rem] = v;
      }
      __syncthreads();
      int r = rb * 64 + lane;
      if (r < 300){
        int c0 = team, c1 = team + 4;
        bool v1 = c1 < 6;
        float a0 = 0.f, a1 = 0.f;
        const float* wp = Wcm + (size_t)r * 1200;
        for (int k = 0; k < 1200; k += 4){
          float4 wv = *(const float4*)(wp + k);
          float4 z0 = *(const float4*)(&Z[c0][k]);
          a0 += wv.x*z0.x + wv.y*z0.y + wv.z*z0.z + wv.w*z0.w;
          if (v1){
            float4 z1 = *(const float4*)(&Z[c1][k]);
            a1 += wv.x*z1.x + wv.y*z1.y + wv.z*z1.z + wv.w*z1.w;
          }
        }
        float bb = bcm[r];
        int g0 = colbase + c0;
        if (g0 < TC) astore(&hc[(size_t)g0 * 300 + r], fmaxf(a0 + bb, 0.f));
        if (v1){
          int g1 = colbase + c1;
          if (g1 < TC) astore(&hc[(size_t)g1 * 300 + r], fmaxf(a1 + bb, 0.f));
        }
      }
    }
  }
  gsync<FNB>(bar, (uint32)++ph);

  // ======== compare xg ========
  xg_tiles(Wx_c, bx_c, hc, xg_c, b, FNB);
  gsync<FNB>(bar, (uint32)++ph);

  // ======== compare tree ========
  tree_stage(Wl_c, Wr_c, xg_c);

  // ======== aggregate mean/max per (tree, m) ========
  {
    for (int idx = b; idx < 600; idx += FNB){
      int tr = idx / 300, mm = idx - tr * 300;
      const float* p = HT + (size_t)mm * HTLD + tr * NN;
      float v = 0.f, vm = -1e30f;
      if (tid < NN){ v = aload(&p[tid]); vm = v; }
      __syncthreads();
      red_s[tid] = v; __syncthreads();
      for (int s = 128; s; s >>= 1){ if (tid < s) red_s[tid] += red_s[tid + s]; __syncthreads(); }
      float sum = red_s[0]; __syncthreads();
      red_s[tid] = vm; __syncthreads();
      for (int s = 128; s; s >>= 1){ if (tid < s) red_s[tid] = fmaxf(red_s[tid], red_s[tid + s]); __syncthreads(); }
      if (tid == 0){
        astore(&agg[tr * 600 + mm], sum / 255.f);
        astore(&agg[tr * 600 + 300 + mm], red_s[0]);
      }
      __syncthreads();
    }
  }
  gsync<FNB>(bar, (uint32)++ph);

  // ======== MLP head (block 0) ========
  if (b == 0){
    float* a_s = ubuf;
    float* hid = ubuf + 1200;
    for (int k = tid; k < 1200; k += 256) a_s[k] = aload(&agg[k]);
    __syncthreads();
    for (int h = tid; h < 300; h += 256){
      float acc = ba1[h];
      const float* wp = Wa1 + (size_t)h * 1200;
      for (int k = 0; k < 1200; k += 4){
        float4 wv = *(const float4*)(wp + k);
        float4 av = *(const float4*)(&a_s[k]);
        acc += wv.x*av.x + wv.y*av.y + wv.z*av.z + wv.w*av.w;
      }
      hid[h] = fmaxf(acc, 0.f);
    }
    __syncthreads();
    if (tid < 192){
      int c = tid >> 6, ln = tid & 63;
      float a = 0.f;
      for (int k = ln; k < 300; k += 64) a += Wa2[c * 300 + k] * hid[k];
      #pragma unroll
      for (int off = 32; off; off >>= 1) a += __shfl_down(a, off);
      if (ln == 0) out[c] = a + ba2[c];
    }
  }
}

// ====================== FALLBACK: proven round-5 pipeline ======================

__global__ __launch_bounds__(512) void k_setup(const int* __restrict__ l1, const int* __restrict__ r1,
                                               const int* __restrict__ l2, const int* __restrict__ r2,
                                               int4* __restrict__ lists2, int* __restrict__ cnt)
{
  __shared__ int lv[TC];
  __shared__ int cs[16];
  int t = threadIdx.x;
  if (t < TC) lv[t] = 0;
  if (t < 16) cs[t] = 0;
  __syncthreads();
  for (int it = 0; it < 12; ++it){
    int nv = 0;
    if (t < TC){
      int tr = t >= NN, i = t - tr * NN;
      const int* L = tr ? l2 : l1;
      const int* R = tr ? r2 : r1;
      int l = L[i], r = R[i];
      nv = (l < 0) ? 0 : 1 + max(lv[tr * NN + l], lv[tr * NN + r]);
    }
    __syncthreads();
    if (t < TC) lv[t] = nv;
    __syncthreads();
  }
  if (t < TC){
    int tr = t >= NN, i = t - tr * NN;
    int v = min(lv[t], 15);
    int pos = atomicAdd(&cs[v], 1);
    int l = (tr ? l2 : l1)[i], r = (tr ? r2 : r1)[i];
    lists2[v * 256 + pos] = make_int4(tr * NN + i, tr * NN + max(l, 0), tr * NN + max(r, 0), 0);
  }
  __syncthreads();
  if (t < 16) cnt[t] = cs[t];
}

__global__ __launch_bounds__(256, 2) void k_tree(
    const int* __restrict__ l1, const int* __restrict__ l2,
    const float* __restrict__ Wl, const float* __restrict__ Wr,
    const float* __restrict__ xg,
    float* __restrict__ H, float* __restrict__ C, float* __restrict__ HT,
    const int4* __restrict__ lists2, const int* __restrict__ cnt,
    uint32* __restrict__ bar)
{
  __shared__ float Hs[BCH][2][320];
  __shared__ float Cs[BCH][4][2];
  __shared__ float Xs[BCH][4][4];
  __shared__ int4 nfo[288];
  __shared__ int lvoff[9];

  const int tid = threadIdx.x;
  const int lane = tid & 63, team = tid >> 6;
  const int mblk = blockIdx.x % 75, grp = blockIdx.x / 75;
  const int m = mblk * 4 + team;

  float wl[5][5], wr[5][5];
  #pragma unroll
  for (int g = 0; g < 5; ++g)
    #pragma unroll
    for (int j = 0; j < 5; ++j){
      int d = j * 64 + lane;
      size_t o = ((size_t)g * 300 + m) * 300 + d;
      wl[g][j] = (d < 300) ? Wl[o] : 0.f;
      wr[g][j] = (d < 300) ? Wr[o] : 0.f;
    }

  if (tid == 0){ int o = 0; for (int lv = 1; lv <= 7; ++lv){ lvoff[lv] = o; o += cnt[lv]; } }
  __syncthreads();
  for (int lv = 1; lv <= 7; ++lv)
    for (int i = tid; i < cnt[lv]; i += 256)
      nfo[lvoff[lv] + i] = lists2[lv * 256 + i];

  for (int e = blockIdx.x * 256 + tid; e < TC * 300; e += 256 * BNB){
    int gi = e / 300, mm = e - gi * 300;
    int tr = gi >= NN, node = gi - tr * NN;
    if ((tr ? l2 : l1)[node] < 0){
      float c, h; leaf_gate(xg + (size_t)gi * 1200, mm, c, h);
      astore(&C[(size_t)gi * 300 + mm], c);
      astore(&H[(size_t)gi * 300 + mm], h);
      astore(&HT[(size_t)mm * HTLD + gi], h);
    }
  }
  gsync<BNB>(bar, 1);

  for (int lv = 1; lv <= 7; ++lv){
    int nodes = cnt[lv];
    int npg = (nodes + 3) >> 2;
    int n0 = grp * npg, n1 = min(nodes, n0 + npg);
    for (int nb0 = n0; nb0 < n1; nb0 += BCH){
      int nch = min(BCH, n1 - nb0);
      int base = lvoff[lv] + nb0;
      __syncthreads();
      #pragma unroll
      for (int p = 0; p < 2; ++p){
        int niA = team + p * 8, niB = niA + 4;
        bool vA = niA < nch, vB = niB < nch;
        int4 na = vA ? nfo[base + niA] : make_int4(0, 0, 0, 0);
        int4 nb4 = vB ? nfo[base + niB] : make_int4(0, 0, 0, 0);
        int d0 = lane, d1 = 64 + lane, d2 = 128 + lane, d3 = 192 + lane, d4 = 256 + lane;
        bool i4 = d4 < 300;
        #define LDH(ci, dd, ok) ((ok) ? aload(&H[(size_t)(ci) * 300 + (dd)]) : 0.f)
        float a0=LDH(na.y,d0,vA), a1=LDH(na.y,d1,vA), a2=LDH(na.y,d2,vA), a3=LDH(na.y,d3,vA), a4=LDH(na.y,d4,vA&&i4);
        float a5=LDH(na.z,d0,vA), a6=LDH(na.z,d1,vA), a7=LDH(na.z,d2,vA), a8=LDH(na.z,d3,vA), a9=LDH(na.z,d4,vA&&i4);
        float c0=LDH(nb4.y,d0,vB), c1=LDH(nb4.y,d1,vB), c2=LDH(nb4.y,d2,vB), c3=LDH(nb4.y,d3,vB), c4=LDH(nb4.y,d4,vB&&i4);
        float c5=LDH(nb4.z,d0,vB), c6=LDH(nb4.z,d1,vB), c7=LDH(nb4.z,d2,vB), c8=LDH(nb4.z,d3,vB), c9=LDH(nb4.z,d4,vB&&i4);
        #undef LDH
        if (vA){
          Hs[niA][0][d0]=a0; Hs[niA][0][d1]=a1; Hs[niA][0][d2]=a2; Hs[niA][0][d3]=a3; Hs[niA][0][d4]=a4;
          Hs[niA][1][d0]=a5; Hs[niA][1][d1]=a6; Hs[niA][1][d2]=a7; Hs[niA][1][d3]=a8; Hs[niA][1][d4]=a9;
        }
        if (vB){
          Hs[niB][0][d0]=c0; Hs[niB][0][d1]=c1; Hs[niB][0][d2]=c2; Hs[niB][0][d3]=c3; Hs[niB][0][d4]=c4;
          Hs[niB][1][d0]=c5; Hs[niB][1][d1]=c6; Hs[niB][1][d2]=c7; Hs[niB][1][d3]=c8; Hs[niB][1][d4]=c9;
        }
      }
      if (tid < 128){
        int ni = tid >> 3, tm = (tid >> 1) & 3, side = tid & 1;
        if (ni < nch){
          int4 nn = nfo[base + ni];
          int child = side ? nn.z : nn.y;
          Cs[ni][tm][side] = aload(&C[(size_t)child * 300 + mblk * 4 + tm]);
        }
      }
      {
        int ni = tid >> 4, tm = (tid >> 2) & 3, g = tid & 3;
        if (ni < nch){
          int4 nn = nfo[base + ni];
          Xs[ni][tm][g] = xg[(size_t)nn.x * 1200 + g * 300 + mblk * 4 + tm];
        }
      }
      __syncthreads();
      #pragma unroll 2
      for (int ni = 0; ni < nch; ++ni){
        float p0 = 0.f, p1 = 0.f, p2 = 0.f, p3 = 0.f, p4 = 0.f;
        #pragma unroll
        for (int j = 0; j < 5; ++j){
          float hl = Hs[ni][0][j * 64 + lane];
          float hr = Hs[ni][1][j * 64 + lane];
          p0 += wl[0][j] * hl + wr[0][j] * hr;
          p1 += wl[1][j] * hl + wr[1][j] * hr;
          p2 += wl[2][j] * hl + wr[2][j] * hr;
          p3 += wl[3][j] * hl + wr[3][j] * hr;
          p4 += wl[4][j] * hl + wr[4][j] * hr;
        }
        #pragma unroll
        for (int off = 32; off; off >>= 1){
          p0 += __shfl_xor(p0, off); p1 += __shfl_xor(p1, off); p2 += __shfl_xor(p2, off);
          p3 += __shfl_xor(p3, off); p4 += __shfl_xor(p4, off);
        }
        if (lane == 0){
          int4 nn = nfo[base + ni];
          int gi = nn.x;
          float lc = Cs[ni][team][0], rc = Cs[ni][team][1];
          float u  = tanhf(Xs[ni][team][0] + p0);
          float ig = sigm (Xs[ni][team][1] + p1);
          float lf = sigm (Xs[ni][team][2] + p2);
          float rf = sigm (Xs[ni][team][2] + p3);
          float o  = sigm (Xs[ni][team][3] + p4);
          float cc = ig * u + lf * lc + rf * rc;
          float hv = o * tanhf(cc);
          astore(&C[(size_t)gi * 300 + m], cc);
          astore(&H[(size_t)gi * 300 + m], hv);
          astore(&HT[(size_t)m * HTLD + gi], hv);
        }
      }
    }
    if (lv < 7) gsync<BNB>(bar, 1 + lv);
  }
}

__global__ __launch_bounds__(256) void k_xg(const int* __restrict__ sent1, const int* __restrict__ sent2,
                                            const int* __restrict__ l1, const int* __restrict__ l2,
                                            const float* __restrict__ emb, int pad,
                                            const float* __restrict__ W, const float* __restrict__ bias,
                                            const float* __restrict__ hsrc, float* __restrict__ out)
{
  __shared__ float Z[8][300];
  int tx = threadIdx.x, ty = threadIdx.y;
  int t = ty * 64 + tx;
  int colbase = blockIdx.y * 8;
  for (int c = 0; c < 8; ++c){
    int gcol = colbase + c;
    if (gcol < TC){
      if (hsrc){
        for (int k = t; k < 300; k += 256) Z[c][k] = hsrc[(size_t)gcol * 300 + k];
      } else {
        int tr = gcol >= NN, node = gcol - tr * NN;
        int tok = ((tr ? l2 : l1)[node] < 0) ? (tr ? sent2 : sent1)[node] : pad;
        const float* e = emb + (size_t)tok * 300;
        for (int k = t; k < 300; k += 256) Z[c][k] = e[k];
      }
    } else {
      for (int k = t; k < 300; k += 256) Z[c][k] = 0.f;
    }
  }
  __syncthreads();
  int r = blockIdx.x * 64 + tx;
  if (r < 1200){
    float a0 = 0.f, a1 = 0.f;
    const float* wp = W + (size_t)r * 300;
    for (int k = 0; k < 300; k += 4){
      float4 wv = *(const float4*)(wp + k);
      float4 z0 = *(const float4*)(&Z[ty][k]);
      float4 z1 = *(const float4*)(&Z[ty + 4][k]);
      a0 += wv.x*z0.x + wv.y*z0.y + wv.z*z0.z + wv.w*z0.w;
      a1 += wv.x*z1.x + wv.y*z1.y + wv.z*z1.z + wv.w*z1.w;
    }
    float b = bias[r];
    int g0 = colbase + ty, g1 = colbase + ty + 4;
    if (g0 < TC) out[(size_t)g0 * 1200 + r] = a0 + b;
    if (g1 < TC) out[(size_t)g1 * 1200 + r] = a1 + b;
  }
}

__global__ __launch_bounds__(256) void k_attn(const float* __restrict__ H, const float* __restrict__ HT,
                                              float* __restrict__ ab)
{
  __shared__ float q[300];
  __shared__ float pr[NN];
  __shared__ float red[256];
  int b = blockIdx.x, t = threadIdx.x;
  int dir = b >= NN, i = b - dir * NN;
  const float* Ss = H + (dir ? NN * 300 : 0);
  const float* So = H + (dir ? 0 : NN * 300);
  int oppb = dir ? 0 : NN;
  for (int k = t; k < 300; k += 256) q[k] = Ss[(size_t)i * 300 + k];
  __syncthreads();
  float v = -1e30f;
  if (t < NN){
    float a = 0.f;
    const float* hp = HT + oppb + t;
    #pragma unroll 4
    for (int k = 0; k < 300; ++k) a += q[k] * hp[(size_t)k * HTLD];
    pr[t] = a; v = a;
  }
  red[t] = v; __syncthreads();
  for (int s = 128; s; s >>= 1){ if (t < s) red[t] = fmaxf(red[t], red[t + s]); __syncthreads(); }
  float mx = red[0]; __syncthreads();
  float e = 0.f;
  if (t < NN){ e = expf(pr[t] - mx); pr[t] = e; }
  red[t] = e; __syncthreads();
  for (int s = 128; s; s >>= 1){ if (t < s) red[t] += red[t + s]; __syncthreads(); }
  float inv = 1.f / red[0]; __syncthreads();
  for (int m = t; m < 300; m += 256){
    float a = 0.f;
    for (int j = 0; j < NN; ++j) a += pr[j] * So[(size_t)j * 300 + m];
    ab[(size_t)b * 300 + m] = a * inv;
  }
}

__global__ __launch_bounds__(256) void k_hcmp(const float* __restrict__ Henc, const float* __restrict__ ab,
                                              const float* __restrict__ Wc, const float* __restrict__ bc,
                                              float* __restrict__ hc)
{
  __shared__ float Z[8][1200];
  int tx = threadIdx.x, ty = threadIdx.y;
  int t = ty * 64 + tx;
  int colbase = blockIdx.y * 8;
  for (int c = 0; c < 8; ++c){
    int gcol = colbase + c;
    if (gcol < TC){
      const float* sp = Henc + (size_t)gcol * 300;
      const float* ap = ab + (size_t)gcol * 300;
      for (int k = t; k < 1200; k += 256){
        int sel = k >= 900 ? 3 : (k >= 600 ? 2 : (k >= 300 ? 1 : 0));
        int kk = k - sel * 300;
        float s = sp[kk], a = ap[kk];
        Z[c][k] = sel == 0 ? s : sel == 1 ? a : sel == 2 ? (s - a) : (s * a);
      }
    } else {
      for (int k = t; k < 1200; k += 256) Z[c][k] = 0.f;
    }
  }
  __syncthreads();
  int r = blockIdx.x * 64 + tx;
  if (r < 300){
    float a0 = 0.f, a1 = 0.f;
    const float* wp = Wc + (size_t)r * 1200;
    for (int k = 0; k < 1200; k += 4){
      float4 wv = *(const float4*)(wp + k);
      float4 z0 = *(const float4*)(&Z[ty][k]);
      float4 z1 = *(const float4*)(&Z[ty + 4][k]);
      a0 += wv.x*z0.x + wv.y*z0.y + wv.z*z0.z + wv.w*z0.w;
      a1 += wv.x*z1.x + wv.y*z1.y + wv.z*z1.z + wv.w*z1.w;
    }
    float b = bc[r];
    int g0 = colbase + ty, g1 = colbase + ty + 4;
    if (g0 < TC) hc[(size_t)g0 * 300 + r] = fmaxf(a0 + b, 0.f);
    if (g1 < TC) hc[(size_t)g1 * 300 + r] = fmaxf(a1 + b, 0.f);
  }
}

__global__ __launch_bounds__(512) void k_head(const float* __restrict__ HTc,
                                              const float* __restrict__ Wa1, const float* __restrict__ ba1,
                                              const float* __restrict__ Wa2, const float* __restrict__ ba2,
                                              float* __restrict__ out)
{
  __shared__ float a_s[1200];
  __shared__ float hid[300];
  int t = threadIdx.x;
  for (int idx = t; idx < 600; idx += 512){
    int tr = idx >= 300;
    int m = idx - tr * 300;
    const float* p = HTc + (size_t)m * HTLD + tr * NN;
    float s = 0.f, mx = -1e30f;
    for (int n = 0; n < NN; ++n){ float v = p[n]; s += v; mx = fmaxf(mx, v); }
    a_s[tr * 600 + m] = s / 255.0f;
    a_s[tr * 600 + 300 + m] = mx;
  }
  __syncthreads();
  for (int h = t; h < 300; h += 512){
    float acc = ba1[h];
    const float* wp = Wa1 + (size_t)h * 1200;
    for (int k = 0; k < 1200; k += 4){
      float4 wv = *(const float4*)(wp + k);
      float4 av = *(const float4*)(&a_s[k]);
      acc += wv.x*av.x + wv.y*av.y + wv.z*av.z + wv.w*av.w;
    }
    hid[h] = fmaxf(acc, 0.f);
  }
  __syncthreads();
  if (t < 192){
    int c = t >> 6, lane = t & 63;
    float a = 0.f;
    for (int k = lane; k < 300; k += 64) a += Wa2[c * 300 + k] * hid[k];
    for (int off = 32; off; off >>= 1) a += __shfl_down(a, off);
    if (lane == 0) out[c] = a + ba2[c];
  }
}

extern "C" void kernel_launch(void* const* d_in, const int* in_sizes, int n_in,
                              void* d_out, int out_size, void* d_ws, size_t ws_size,
                              hipStream_t stream)
{
  const int*   sent1 = (const int*)d_in[0];
  const int*   sent2 = (const int*)d_in[1];
  const int*   l1    = (const int*)d_in[2];
  const int*   r1    = (const int*)d_in[3];
  const int*   l2    = (const int*)d_in[4];
  const int*   r2    = (const int*)d_in[5];
  const float* emb   = (const float*)d_in[6];
  const float* Wx_i  = (const float*)d_in[7];
  const float* bx_i  = (const float*)d_in[8];
  const float* Wl_i  = (const float*)d_in[9];
  const float* Wr_i  = (const float*)d_in[10];
  const float* Wx_c  = (const float*)d_in[11];
  const float* bx_c  = (const float*)d_in[12];
  const float* Wl_c  = (const float*)d_in[13];
  const float* Wr_c  = (const float*)d_in[14];
  const float* Wcm   = (const float*)d_in[15];
  const float* bcm   = (const float*)d_in[16];
  const float* Wa1   = (const float*)d_in[17];
  const float* ba1   = (const float*)d_in[18];
  const float* Wa2   = (const float*)d_in[19];
  const float* ba2   = (const float*)d_in[20];
  int V = in_sizes[6] / 300;
  int pad = V - 1;

  char* w = (char*)d_ws;
  uint32* bar    = (uint32*)w;                 // 0..4096: fused flags[600]+gate; fallback bar1 @0, bar2 @2048
  uint32* bar2   = (uint32*)(w + 2048);
  int*    cnt    = (int*)(w + 8192);           // 16 ints (shared by both paths)
  uint32* listsP = (uint32*)(w + 8256);        // fused packed lists 16*256 u32
  int4*   lists2 = (int4*)(w + 24640);         // fallback int4 lists 16*256
  float* fb   = (float*)(w + 90176);
  float* xg_e = fb;                            // [510][1200]
  float* xg_c = xg_e + 612000;                 // [510][1200] (fallback: Hcmp @ +0, HTc @ +153000)
  float* H    = xg_c + 612000;                 // [510][300]
  float* C    = H + 153000;                    // [510][300]
  float* ab   = C + 153000;                    // [510][300]
  float* hc   = ab + 153000;                   // [510][300]
  float* HT   = hc + 153000;                   // [300][512]
  float* agg  = HT + 153600;                   // [1200]
  float* outp = (float*)d_out;

  hipMemsetAsync(bar, 0, 4096, stream);

  // ---- gate the fused launch on actual occupancy (pure host queries, capture-safe) ----
  int nbF = 0, nCU = 0;
  hipError_t eq = hipOccupancyMaxActiveBlocksPerMultiprocessor(&nbF, reinterpret_cast<const void*>(k_all), 256, 0);
  hipError_t ec = hipDeviceGetAttribute(&nCU, hipDeviceAttributeMultiprocessorCount, 0);
  bool fusedOK = (eq == hipSuccess) && (ec == hipSuccess) && (nbF * nCU >= FNB);

  if (fusedOK){
    void* args[] = { (void*)&sent1,(void*)&sent2,(void*)&l1,(void*)&r1,(void*)&l2,(void*)&r2,
                     (void*)&emb,(void*)&pad,
                     (void*)&Wx_i,(void*)&bx_i,(void*)&Wl_i,(void*)&Wr_i,
                     (void*)&Wx_c,(void*)&bx_c,(void*)&Wl_c,(void*)&Wr_c,
                     (void*)&Wcm,(void*)&bcm,(void*)&Wa1,(void*)&ba1,(void*)&Wa2,(void*)&ba2,
                     (void*)&outp,
                     (void*)&xg_e,(void*)&xg_c,(void*)&H,(void*)&C,(void*)&ab,(void*)&hc,
                     (void*)&HT,(void*)&agg,(void*)&listsP,(void*)&cnt,(void*)&bar };
    hipError_t el = hipLaunchCooperativeKernel((void*)k_all, dim3(FNB), dim3(256), args, 0, stream);
    if (el == hipSuccess) return;
    (void)hipGetLastError();   // clear sticky error; fall through to proven path
  }

  // ---- fallback: proven round-5 multi-kernel pipeline ----
  float* Hcmp = xg_c;             // reuse xg_c region (free in fallback)
  float* HTc  = xg_c + 153000;

  k_setup<<<1, 512, 0, stream>>>(l1, r1, l2, r2, lists2, cnt);
  dim3 blk(64, 4);
  k_xg<<<dim3(19, 64), blk, 0, stream>>>(sent1, sent2, l1, l2, emb, pad, Wx_i, bx_i, nullptr, xg_e);
  {
    void* args[] = {(void*)&l1, (void*)&l2, (void*)&Wl_i, (void*)&Wr_i, (void*)&xg_e,
                    (void*)&H, (void*)&C, (void*)&HT, (void*)&lists2, (void*)&cnt, (void*)&bar};
    hipLaunchCooperativeKernel((void*)k_tree, dim3(BNB), dim3(256), args, 0, stream);
  }
  k_attn<<<TC, 256, 0, stream>>>(H, HT, ab);
  k_hcmp<<<dim3(5, 64), blk, 0, stream>>>(H, ab, Wcm, bcm, hc);
  k_xg<<<dim3(19, 64), blk, 0, stream>>>(sent1, sent2, l1, l2, emb, pad, Wx_c, bx_c, hc, xg_e);
  {
    void* args[] = {(void*)&l1, (void*)&l2, (void*)&Wl_c, (void*)&Wr_c, (void*)&xg_e,
                    (void*)&Hcmp, (void*)&C, (void*)&HTc, (void*)&lists2, (void*)&cnt, (void*)&bar2};
    hipLaunchCooperativeKernel((void*)k_tree, dim3(BNB), dim3(256), args, 0, stream);
  }
  k_head<<<1, 512, 0, stream>>>(HTc, Wa1, ba1, Wa2, ba2, outp);
}